// Round 1
// baseline (659.818 us; speedup 1.0000x reference)
//
#include <hip/hip_runtime.h>
#include <stdint.h>

typedef unsigned short u16;
typedef __attribute__((ext_vector_type(8))) short short8;
typedef __attribute__((ext_vector_type(4))) float f32x4;
typedef __attribute__((ext_vector_type(4))) u16 u16x4;

#define NB 4
#define SEQ 2048
#define DM 1024
#define NH 16
#define DKh 64
#define DFF 4096

__device__ __forceinline__ u16 f2bf(float f) {
  union { float f; uint32_t u; } v; v.f = f;
  uint32_t u = v.u;
  return (u16)((u + 0x7FFFu + ((u >> 16) & 1u)) >> 16);
}

// ---- transpose + fp32->bf16: dst[C][R] = bf16(src[R][C]) ----
__global__ __launch_bounds__(256) void transpose_bf16(const float* __restrict__ src,
                                                      u16* __restrict__ dst, int R, int C) {
  __shared__ float tile[32][33];
  int tx = threadIdx.x, ty = threadIdx.y;
  int c0 = blockIdx.x * 32, r0 = blockIdx.y * 32;
#pragma unroll
  for (int i = 0; i < 32; i += 8)
    tile[ty + i][tx] = src[(size_t)(r0 + ty + i) * C + c0 + tx];
  __syncthreads();
#pragma unroll
  for (int i = 0; i < 32; i += 8)
    dst[(size_t)(c0 + ty + i) * R + r0 + tx] = f2bf(tile[tx][ty + i]);
}

// ---- custom LayerNorm (scalar alpha/beta, unbiased std, eps on std) -> bf16 ----
__global__ __launch_bounds__(256) void ln_bf16(const float* __restrict__ x,
                                               u16* __restrict__ out,
                                               const float* __restrict__ alpha,
                                               const float* __restrict__ beta) {
  int row = blockIdx.x;
  const float4* xr = (const float4*)(x + (size_t)row * DM);
  int t = threadIdx.x;
  float4 v = xr[t];
  float s = v.x + v.y + v.z + v.w;
  float s2 = v.x * v.x + v.y * v.y + v.z * v.z + v.w * v.w;
#pragma unroll
  for (int m = 1; m < 64; m <<= 1) { s += __shfl_xor(s, m); s2 += __shfl_xor(s2, m); }
  __shared__ float red[8];
  int wid = t >> 6, lane = t & 63;
  if (lane == 0) { red[wid] = s; red[wid + 4] = s2; }
  __syncthreads();
  float S = red[0] + red[1] + red[2] + red[3];
  float S2 = red[4] + red[5] + red[6] + red[7];
  float mean = S * (1.0f / DM);
  float var = fmaxf((S2 - S * mean) * (1.0f / (DM - 1)), 0.0f);
  float inv = alpha[0] / (sqrtf(var) + 1e-6f);
  float bet = beta[0];
  u16x4 o;
  o[0] = f2bf((v.x - mean) * inv + bet);
  o[1] = f2bf((v.y - mean) * inv + bet);
  o[2] = f2bf((v.z - mean) * inv + bet);
  o[3] = f2bf((v.w - mean) * inv + bet);
  *(u16x4*)(out + (size_t)row * DM + t * 4) = o;
}

// ---- GEMM: C[M,N] = A[M,K](bf16) @ W^T[N,K](bf16) + bias, epilogue by MODE ----
// MODE 0: out bf16 scatter to [B,H,S,DKh], val=(acc+bias)*scale   (Q/K)
// MODE 1: out bf16 scatter to [B,H,DKh,S] (V transposed)
// MODE 2: out fp32 row-major [M,N], val = resid + acc + bias
// MODE 3: out bf16 row-major [M,N], val = relu(acc + bias)
template <int MODE>
__global__ __launch_bounds__(256) void gemm_bf16(const u16* __restrict__ A,
                                                 const u16* __restrict__ WT,
                                                 const float* __restrict__ bias,
                                                 const float* __restrict__ resid,
                                                 void* __restrict__ outp,
                                                 int M, int N, int K, float scale) {
  __shared__ u16 As[128 * 64];
  __shared__ u16 Bs[128 * 64];
  int tid = threadIdx.x;
  int wid = tid >> 6, lane = tid & 63;
  int lr = lane & 15, lg = lane >> 4;
  int m0 = blockIdx.y * 128, n0 = blockIdx.x * 128;
  int wm = (wid >> 1) * 64, wn = (wid & 1) * 64;
  f32x4 acc[4][4] = {};
  for (int kt = 0; kt < K; kt += 64) {
    short8 va[4], vb[4];
#pragma unroll
    for (int it = 0; it < 4; ++it) {
      int ee = it * 2048 + tid * 8;
      int r = ee >> 6, c = ee & 63;
      va[it] = *(const short8*)(A + (size_t)(m0 + r) * K + kt + c);
      vb[it] = *(const short8*)(WT + (size_t)(n0 + r) * K + kt + c);
    }
    __syncthreads();
#pragma unroll
    for (int it = 0; it < 4; ++it) {
      int ee = it * 2048 + tid * 8;
      *(short8*)&As[ee] = va[it];
      *(short8*)&Bs[ee] = vb[it];
    }
    __syncthreads();
#pragma unroll
    for (int kk = 0; kk < 2; ++kk) {
      short8 af[4], bf[4];
#pragma unroll
      for (int i = 0; i < 4; ++i)
        af[i] = *(const short8*)&As[(wm + i * 16 + lr) * 64 + kk * 32 + lg * 8];
#pragma unroll
      for (int j = 0; j < 4; ++j)
        bf[j] = *(const short8*)&Bs[(wn + j * 16 + lr) * 64 + kk * 32 + lg * 8];
#pragma unroll
      for (int i = 0; i < 4; ++i)
#pragma unroll
        for (int j = 0; j < 4; ++j)
          acc[i][j] = __builtin_amdgcn_mfma_f32_16x16x32_bf16(af[i], bf[j], acc[i][j], 0, 0, 0);
    }
  }
#pragma unroll
  for (int i = 0; i < 4; ++i) {
#pragma unroll
    for (int j = 0; j < 4; ++j) {
      int col = n0 + wn + j * 16 + lr;
      float bi = bias[col];
      int rbase = m0 + wm + i * 16 + lg * 4;
      if (MODE == 0) {
        u16* q = (u16*)outp;
        int hh = col >> 6, dd = col & 63;
#pragma unroll
        for (int r = 0; r < 4; ++r) {
          int row = rbase + r;
          int bb = row >> 11, ss = row & 2047;
          q[((size_t)(bb * NH + hh) * SEQ + ss) * DKh + dd] = f2bf((acc[i][j][r] + bi) * scale);
        }
      } else if (MODE == 1) {
        u16* vt = (u16*)outp;
        int hh = col >> 6, dd = col & 63;
        int bb = rbase >> 11, ss = rbase & 2047;
        u16x4 pk;
#pragma unroll
        for (int r = 0; r < 4; ++r) pk[r] = f2bf(acc[i][j][r] + bi);
        *(u16x4*)&vt[((size_t)(bb * NH + hh) * DKh + dd) * SEQ + ss] = pk;
      } else if (MODE == 2) {
        float* o = (float*)outp;
#pragma unroll
        for (int r = 0; r < 4; ++r) {
          int row = rbase + r;
          size_t idx = (size_t)row * N + col;
          o[idx] = resid[idx] + acc[i][j][r] + bi;
        }
      } else {
        u16* o = (u16*)outp;
#pragma unroll
        for (int r = 0; r < 4; ++r) {
          int row = rbase + r;
          o[(size_t)row * N + col] = f2bf(fmaxf(acc[i][j][r] + bi, 0.0f));
        }
      }
    }
  }
}

// ---- flash attention: q pre-scaled; k [B,H,S,64]; vt [B,H,64,S]; out ctx bf16 [B,S,DM] ----
__global__ __launch_bounds__(256) void attn_fwd(const u16* __restrict__ q,
                                                const u16* __restrict__ k,
                                                const u16* __restrict__ vt,
                                                const int* __restrict__ mask,
                                                u16* __restrict__ ctx) {
  __shared__ u16 Ks[64 * 64];
  __shared__ u16 Vs[64 * 64];
  __shared__ u16 Ps[4][32 * 64];
  int tid = threadIdx.x;
  int wid = tid >> 6, lane = tid & 63;
  int lr = lane & 15, lg = lane >> 4;
  int bh = blockIdx.y;
  int b = bh >> 4, hh = bh & 15;
  int q0 = blockIdx.x * 128;
  const u16* qbase = q + (size_t)bh * SEQ * DKh;
  const u16* kbase = k + (size_t)bh * SEQ * DKh;
  const u16* vbase = vt + (size_t)bh * DKh * SEQ;
  const int* mbase = mask + b * SEQ;
  short8 qf[2][2];
#pragma unroll
  for (int i = 0; i < 2; ++i)
#pragma unroll
    for (int kk = 0; kk < 2; ++kk)
      qf[i][kk] = *(const short8*)(qbase + (size_t)(q0 + wid * 32 + i * 16 + lr) * DKh + kk * 32 + lg * 8);
  f32x4 o[2][4] = {};
  float mrow[2][4], lsum[2][4];
#pragma unroll
  for (int i = 0; i < 2; ++i)
#pragma unroll
    for (int r = 0; r < 4; ++r) { mrow[i][r] = -3e38f; lsum[i][r] = 0.0f; }
  for (int kv0 = 0; kv0 < SEQ; kv0 += 64) {
    short8 ka[2], va[2];
#pragma unroll
    for (int it = 0; it < 2; ++it) {
      int ee = it * 2048 + tid * 8;
      int r = ee >> 6, c = ee & 63;
      ka[it] = *(const short8*)(kbase + (size_t)(kv0 + r) * DKh + c);
      va[it] = *(const short8*)(vbase + (size_t)r * SEQ + kv0 + c);
    }
    __syncthreads();
#pragma unroll
    for (int it = 0; it < 2; ++it) {
      int ee = it * 2048 + tid * 8;
      *(short8*)&Ks[ee] = ka[it];
      *(short8*)&Vs[ee] = va[it];
    }
    __syncthreads();
    f32x4 sc[2][4] = {};
#pragma unroll
    for (int kk = 0; kk < 2; ++kk) {
      short8 kf[4];
#pragma unroll
      for (int j = 0; j < 4; ++j)
        kf[j] = *(const short8*)&Ks[(j * 16 + lr) * 64 + kk * 32 + lg * 8];
#pragma unroll
      for (int i = 0; i < 2; ++i)
#pragma unroll
        for (int j = 0; j < 4; ++j)
          sc[i][j] = __builtin_amdgcn_mfma_f32_16x16x32_bf16(qf[i][kk], kf[j], sc[i][j], 0, 0, 0);
    }
    int mcol[4];
#pragma unroll
    for (int j = 0; j < 4; ++j) mcol[j] = mbase[kv0 + j * 16 + lr];
#pragma unroll
    for (int i = 0; i < 2; ++i)
#pragma unroll
      for (int j = 0; j < 4; ++j)
        if (mcol[j] == 0) {
#pragma unroll
          for (int r = 0; r < 4; ++r) sc[i][j][r] = -1e9f;
        }
#pragma unroll
    for (int i = 0; i < 2; ++i) {
#pragma unroll
      for (int r = 0; r < 4; ++r) {
        float mx = fmaxf(fmaxf(sc[i][0][r], sc[i][1][r]), fmaxf(sc[i][2][r], sc[i][3][r]));
#pragma unroll
        for (int msk = 1; msk < 16; msk <<= 1) mx = fmaxf(mx, __shfl_xor(mx, msk));
        float mnew = fmaxf(mrow[i][r], mx);
        float corr = __expf(mrow[i][r] - mnew);
        float ps = 0.0f;
        u16 pb[4];
#pragma unroll
        for (int j = 0; j < 4; ++j) {
          float p = __expf(sc[i][j][r] - mnew);
          ps += p;
          pb[j] = f2bf(p);
        }
#pragma unroll
        for (int msk = 1; msk < 16; msk <<= 1) ps += __shfl_xor(ps, msk);
        mrow[i][r] = mnew;
        lsum[i][r] = lsum[i][r] * corr + ps;
#pragma unroll
        for (int j = 0; j < 4; ++j) o[i][j][r] *= corr;
        int prow = i * 16 + lg * 4 + r;
#pragma unroll
        for (int j = 0; j < 4; ++j) Ps[wid][prow * 64 + j * 16 + lr] = pb[j];
      }
    }
#pragma unroll
    for (int kk = 0; kk < 2; ++kk) {
      short8 pf[2], vf[4];
#pragma unroll
      for (int i = 0; i < 2; ++i)
        pf[i] = *(const short8*)&Ps[wid][(i * 16 + lr) * 64 + kk * 32 + lg * 8];
#pragma unroll
      for (int j = 0; j < 4; ++j)
        vf[j] = *(const short8*)&Vs[(j * 16 + lr) * 64 + kk * 32 + lg * 8];
#pragma unroll
      for (int i = 0; i < 2; ++i)
#pragma unroll
        for (int j = 0; j < 4; ++j)
          o[i][j] = __builtin_amdgcn_mfma_f32_16x16x32_bf16(pf[i], vf[j], o[i][j], 0, 0, 0);
    }
  }
#pragma unroll
  for (int i = 0; i < 2; ++i) {
#pragma unroll
    for (int r = 0; r < 4; ++r) {
      float inv = 1.0f / lsum[i][r];
      int srow = q0 + wid * 32 + i * 16 + lg * 4 + r;
      size_t obase = ((size_t)b * SEQ + srow) * DM + hh * DKh;
#pragma unroll
      for (int j = 0; j < 4; ++j)
        ctx[obase + j * 16 + lr] = f2bf(o[i][j][r] * inv);
    }
  }
}

extern "C" void kernel_launch(void* const* d_in, const int* in_sizes, int n_in,
                              void* d_out, int out_size, void* d_ws, size_t ws_size,
                              hipStream_t stream) {
  const float* x   = (const float*)d_in[0];
  const int*   msk = (const int*)d_in[1];
  const float* wq  = (const float*)d_in[2];
  const float* bq  = (const float*)d_in[3];
  const float* wk  = (const float*)d_in[4];
  const float* bk  = (const float*)d_in[5];
  const float* wv  = (const float*)d_in[6];
  const float* bv  = (const float*)d_in[7];
  const float* wo  = (const float*)d_in[8];
  const float* bo  = (const float*)d_in[9];
  const float* w1  = (const float*)d_in[10];
  const float* b1  = (const float*)d_in[11];
  const float* w2  = (const float*)d_in[12];
  const float* b2  = (const float*)d_in[13];
  const float* a1  = (const float*)d_in[14];
  const float* be1 = (const float*)d_in[15];
  const float* a2  = (const float*)d_in[16];
  const float* be2 = (const float*)d_in[17];
  float* out = (float*)d_out;

  u16* wqT = (u16*)d_ws;
  u16* wkT = wqT + (1u << 20);
  u16* wvT = wkT + (1u << 20);
  u16* woT = wvT + (1u << 20);
  u16* w1T = woT + (1u << 20);
  u16* w2T = w1T + (4u << 20);
  u16* xn  = w2T + (4u << 20);
  u16* qb  = xn  + (8u << 20);
  u16* kb  = qb  + (8u << 20);
  u16* vtb = kb  + (8u << 20);
  u16* ctx = vtb + (8u << 20);
  u16* hb  = qb;  // reuse qb..ctx (exactly 8192*4096 elems) for FFN hidden

  dim3 tb(32, 8);
  transpose_bf16<<<dim3(32, 32), tb, 0, stream>>>(wq, wqT, DM, DM);
  transpose_bf16<<<dim3(32, 32), tb, 0, stream>>>(wk, wkT, DM, DM);
  transpose_bf16<<<dim3(32, 32), tb, 0, stream>>>(wv, wvT, DM, DM);
  transpose_bf16<<<dim3(32, 32), tb, 0, stream>>>(wo, woT, DM, DM);
  transpose_bf16<<<dim3(128, 32), tb, 0, stream>>>(w1, w1T, DM, DFF);
  transpose_bf16<<<dim3(32, 128), tb, 0, stream>>>(w2, w2T, DFF, DM);

  ln_bf16<<<NB * SEQ, 256, 0, stream>>>(x, xn, a1, be1);

  gemm_bf16<0><<<dim3(8, 64), 256, 0, stream>>>(xn, wqT, bq, nullptr, qb, NB * SEQ, DM, DM, 0.125f);
  gemm_bf16<0><<<dim3(8, 64), 256, 0, stream>>>(xn, wkT, bk, nullptr, kb, NB * SEQ, DM, DM, 1.0f);
  gemm_bf16<1><<<dim3(8, 64), 256, 0, stream>>>(xn, wvT, bv, nullptr, vtb, NB * SEQ, DM, DM, 1.0f);

  attn_fwd<<<dim3(SEQ / 128, NB * NH), 256, 0, stream>>>(qb, kb, vtb, msk, ctx);

  gemm_bf16<2><<<dim3(8, 64), 256, 0, stream>>>(ctx, woT, bo, x, out, NB * SEQ, DM, DM, 1.0f);

  ln_bf16<<<NB * SEQ, 256, 0, stream>>>(out, xn, a2, be2);

  gemm_bf16<3><<<dim3(32, 64), 256, 0, stream>>>(xn, w1T, b1, nullptr, hb, NB * SEQ, DFF, DM, 1.0f);
  gemm_bf16<2><<<dim3(8, 64), 256, 0, stream>>>(hb, w2T, b2, out, out, NB * SEQ, DM, DFF, 1.0f);
}

// Round 2
// 575.970 us; speedup vs baseline: 1.1456x; 1.1456x over previous
//
#include <hip/hip_runtime.h>
#include <stdint.h>

typedef unsigned short u16;
typedef __attribute__((ext_vector_type(8))) short short8;
typedef __attribute__((ext_vector_type(4))) float f32x4;
typedef __attribute__((ext_vector_type(4))) u16 u16x4;

#define NB 4
#define SEQ 2048
#define DM 1024
#define NH 16
#define DKh 64
#define DFF 4096

__device__ __forceinline__ u16 f2bf(float f) {
  union { float f; uint32_t u; } v; v.f = f;
  uint32_t u = v.u;
  return (u16)((u + 0x7FFFu + ((u >> 16) & 1u)) >> 16);
}

__device__ __forceinline__ void gl16(const u16* g, u16* l) {
  __builtin_amdgcn_global_load_lds((const __attribute__((address_space(1))) void*)g,
                                   (__attribute__((address_space(3))) void*)l, 16, 0, 0);
}

// ---- transpose + fp32->bf16: dst[C][R] = bf16(src[R][C]) ----
__global__ __launch_bounds__(256) void transpose_bf16(const float* __restrict__ src,
                                                      u16* __restrict__ dst, int R, int C) {
  __shared__ float tile[32][33];
  int tx = threadIdx.x, ty = threadIdx.y;
  int c0 = blockIdx.x * 32, r0 = blockIdx.y * 32;
#pragma unroll
  for (int i = 0; i < 32; i += 8)
    tile[ty + i][tx] = src[(size_t)(r0 + ty + i) * C + c0 + tx];
  __syncthreads();
#pragma unroll
  for (int i = 0; i < 32; i += 8)
    dst[(size_t)(c0 + ty + i) * R + r0 + tx] = f2bf(tile[tx][ty + i]);
}

// ---- custom LayerNorm (scalar alpha/beta, unbiased std, eps on std) -> bf16 ----
__global__ __launch_bounds__(256) void ln_bf16(const float* __restrict__ x,
                                               u16* __restrict__ out,
                                               const float* __restrict__ alpha,
                                               const float* __restrict__ beta) {
  int row = blockIdx.x;
  const float4* xr = (const float4*)(x + (size_t)row * DM);
  int t = threadIdx.x;
  float4 v = xr[t];
  float s = v.x + v.y + v.z + v.w;
  float s2 = v.x * v.x + v.y * v.y + v.z * v.z + v.w * v.w;
#pragma unroll
  for (int m = 1; m < 64; m <<= 1) { s += __shfl_xor(s, m); s2 += __shfl_xor(s2, m); }
  __shared__ float red[8];
  int wid = t >> 6, lane = t & 63;
  if (lane == 0) { red[wid] = s; red[wid + 4] = s2; }
  __syncthreads();
  float S = red[0] + red[1] + red[2] + red[3];
  float S2 = red[4] + red[5] + red[6] + red[7];
  float mean = S * (1.0f / DM);
  float var = fmaxf((S2 - S * mean) * (1.0f / (DM - 1)), 0.0f);
  float inv = alpha[0] / (sqrtf(var) + 1e-6f);
  float bet = beta[0];
  u16x4 o;
  o[0] = f2bf((v.x - mean) * inv + bet);
  o[1] = f2bf((v.y - mean) * inv + bet);
  o[2] = f2bf((v.z - mean) * inv + bet);
  o[3] = f2bf((v.w - mean) * inv + bet);
  *(u16x4*)(out + (size_t)row * DM + t * 4) = o;
}

// ---- GEMM: C[M,N] = A[M,K](bf16) @ W^T[N,K](bf16) + bias, epilogue by MODE ----
// MODE 0: out bf16 scatter to [B,H,S,DKh], val=(acc+bias)*scale   (Q/K)
// MODE 1: out bf16 scatter to [B,H,DKh,S] (V transposed)
// MODE 2: out fp32 row-major [M,N], val = resid + acc + bias
// MODE 3: out bf16 row-major [M,N], val = relu(acc + bias)
template <int MODE>
__global__ __launch_bounds__(256) void gemm_bf16(const u16* __restrict__ A,
                                                 const u16* __restrict__ WT,
                                                 const float* __restrict__ bias,
                                                 const float* __restrict__ resid,
                                                 void* __restrict__ outp,
                                                 int M, int N, int K, float scale) {
  __shared__ u16 As[128 * 64];
  __shared__ u16 Bs[128 * 64];
  int tid = threadIdx.x;
  int wid = tid >> 6, lane = tid & 63;
  int lr = lane & 15, lg = lane >> 4;
  int m0 = blockIdx.y * 128, n0 = blockIdx.x * 128;
  int wm = (wid >> 1) * 64, wn = (wid & 1) * 64;
  int sr = tid >> 3;            // 0..31: staging row within a 32-row chunk
  int sc = (tid & 7) * 8;       // staging col (8 bf16 = 16 B per lane)
  const u16* ag = A + (size_t)(m0 + sr) * K + sc;
  const u16* bg = WT + (size_t)(n0 + sr) * K + sc;
  u16* asl = As + (size_t)(tid & ~63) * 8;   // wave-uniform LDS base (bytes = wid*1024)
  u16* bsl = Bs + (size_t)(tid & ~63) * 8;
  f32x4 acc[4][4] = {};
  for (int kt = 0; kt < K; kt += 64) {
#pragma unroll
    for (int it = 0; it < 4; ++it) {
      gl16(ag + (size_t)(it * 32) * K + kt, asl + it * 2048);
      gl16(bg + (size_t)(it * 32) * K + kt, bsl + it * 2048);
    }
    __syncthreads();
#pragma unroll
    for (int kk = 0; kk < 2; ++kk) {
      short8 af[4], bfr[4];
#pragma unroll
      for (int i = 0; i < 4; ++i)
        af[i] = *(const short8*)&As[(wm + i * 16 + lr) * 64 + kk * 32 + lg * 8];
#pragma unroll
      for (int j = 0; j < 4; ++j)
        bfr[j] = *(const short8*)&Bs[(wn + j * 16 + lr) * 64 + kk * 32 + lg * 8];
#pragma unroll
      for (int i = 0; i < 4; ++i)
#pragma unroll
        for (int j = 0; j < 4; ++j)
          acc[i][j] = __builtin_amdgcn_mfma_f32_16x16x32_bf16(af[i], bfr[j], acc[i][j], 0, 0, 0);
    }
    __syncthreads();
  }
#pragma unroll
  for (int i = 0; i < 4; ++i) {
#pragma unroll
    for (int j = 0; j < 4; ++j) {
      int col = n0 + wn + j * 16 + lr;
      float bi = bias[col];
      int rbase = m0 + wm + i * 16 + lg * 4;
      if (MODE == 0) {
        u16* q = (u16*)outp;
        int hh = col >> 6, dd = col & 63;
#pragma unroll
        for (int r = 0; r < 4; ++r) {
          int row = rbase + r;
          int bb = row >> 11, ss = row & 2047;
          q[((size_t)(bb * NH + hh) * SEQ + ss) * DKh + dd] = f2bf((acc[i][j][r] + bi) * scale);
        }
      } else if (MODE == 1) {
        u16* vt = (u16*)outp;
        int hh = col >> 6, dd = col & 63;
        int bb = rbase >> 11, ss = rbase & 2047;
        u16x4 pk;
#pragma unroll
        for (int r = 0; r < 4; ++r) pk[r] = f2bf(acc[i][j][r] + bi);
        *(u16x4*)&vt[((size_t)(bb * NH + hh) * DKh + dd) * SEQ + ss] = pk;
      } else if (MODE == 2) {
        float* o = (float*)outp;
#pragma unroll
        for (int r = 0; r < 4; ++r) {
          int row = rbase + r;
          size_t idx = (size_t)row * N + col;
          o[idx] = resid[idx] + acc[i][j][r] + bi;
        }
      } else {
        u16* o = (u16*)outp;
#pragma unroll
        for (int r = 0; r < 4; ++r) {
          int row = rbase + r;
          o[(size_t)row * N + col] = f2bf(fmaxf(acc[i][j][r] + bi, 0.0f));
        }
      }
    }
  }
}

// ---- flash attention: q pre-scaled; k [B,H,S,64]; vt [B,H,64,S]; out ctx bf16 [B,S,DM] ----
// LDS tiles XOR-swizzled: element (row, col) lives at row*64 + (col ^ ((row&7)<<3)).
__global__ __launch_bounds__(256) void attn_fwd(const u16* __restrict__ q,
                                                const u16* __restrict__ k,
                                                const u16* __restrict__ vt,
                                                const int* __restrict__ mask,
                                                u16* __restrict__ ctx) {
  __shared__ u16 Ks[64 * 64];
  __shared__ u16 Vs[64 * 64];
  __shared__ u16 Ps[4][32 * 64];
  int tid = threadIdx.x;
  int wid = tid >> 6, lane = tid & 63;
  int lr = lane & 15, lg = lane >> 4;
  int bh = blockIdx.y;
  int b = bh >> 4, hh = bh & 15;
  int q0 = blockIdx.x * 128;
  const u16* qbase = q + (size_t)bh * SEQ * DKh;
  const u16* kbase = k + (size_t)bh * SEQ * DKh;
  const u16* vbase = vt + (size_t)bh * DKh * SEQ;
  const int* mbase = mask + b * SEQ;

  short8 qf[2][2];
#pragma unroll
  for (int i = 0; i < 2; ++i)
#pragma unroll
    for (int kk = 0; kk < 2; ++kk)
      qf[i][kk] = *(const short8*)(qbase + (size_t)(q0 + wid * 32 + i * 16 + lr) * DKh + kk * 32 + lg * 8);

  // staging geometry (reg-staged so we can swizzle the LDS write)
  int sr = tid >> 3;            // 0..31
  int scg = (tid & 7) * 8;
  int wix[2];
#pragma unroll
  for (int it = 0; it < 2; ++it) {
    int r = it * 32 + sr;
    wix[it] = r * 64 + (scg ^ ((r & 7) << 3));
  }
  int swzc = (lr & 7) << 3;     // read-side column XOR (rows are j*16+lr)

  short8 ka[2], va[2];
#pragma unroll
  for (int it = 0; it < 2; ++it) {
    int r = it * 32 + sr;
    ka[it] = *(const short8*)(kbase + (size_t)r * DKh + scg);
    va[it] = *(const short8*)(vbase + (size_t)r * SEQ + scg);
  }

  f32x4 o[2][4] = {};
  float mrow[2][4], lsum[2][4];
#pragma unroll
  for (int i = 0; i < 2; ++i)
#pragma unroll
    for (int r = 0; r < 4; ++r) { mrow[i][r] = -3e38f; lsum[i][r] = 0.0f; }

  for (int kv0 = 0; kv0 < SEQ; kv0 += 64) {
    __syncthreads();            // previous tile fully consumed by all waves
#pragma unroll
    for (int it = 0; it < 2; ++it) {
      *(short8*)&Ks[wix[it]] = ka[it];
      *(short8*)&Vs[wix[it]] = va[it];
    }
    if (kv0 + 64 < SEQ) {       // T14: issue next tile's loads early, consume next iter
      int nv = kv0 + 64;
#pragma unroll
      for (int it = 0; it < 2; ++it) {
        int r = it * 32 + sr;
        ka[it] = *(const short8*)(kbase + (size_t)(nv + r) * DKh + scg);
        va[it] = *(const short8*)(vbase + (size_t)r * SEQ + nv + scg);
      }
    }
    __syncthreads();

    f32x4 s_[2][4] = {};
#pragma unroll
    for (int kk = 0; kk < 2; ++kk) {
      short8 kf[4];
#pragma unroll
      for (int j = 0; j < 4; ++j)
        kf[j] = *(const short8*)&Ks[(j * 16 + lr) * 64 + ((kk * 32 + lg * 8) ^ swzc)];
#pragma unroll
      for (int i = 0; i < 2; ++i)
#pragma unroll
        for (int j = 0; j < 4; ++j)
          s_[i][j] = __builtin_amdgcn_mfma_f32_16x16x32_bf16(qf[i][kk], kf[j], s_[i][j], 0, 0, 0);
    }
    int mcol[4];
#pragma unroll
    for (int j = 0; j < 4; ++j) mcol[j] = mbase[kv0 + j * 16 + lr];
#pragma unroll
    for (int i = 0; i < 2; ++i)
#pragma unroll
      for (int j = 0; j < 4; ++j)
        if (mcol[j] == 0) {
#pragma unroll
          for (int r = 0; r < 4; ++r) s_[i][j][r] = -1e9f;
        }
#pragma unroll
    for (int i = 0; i < 2; ++i) {
#pragma unroll
      for (int r = 0; r < 4; ++r) {
        float mx = fmaxf(fmaxf(s_[i][0][r], s_[i][1][r]), fmaxf(s_[i][2][r], s_[i][3][r]));
#pragma unroll
        for (int mk = 1; mk < 16; mk <<= 1) mx = fmaxf(mx, __shfl_xor(mx, mk));
        float mnew = fmaxf(mrow[i][r], mx);
        float corr = __expf(mrow[i][r] - mnew);
        float ps = 0.0f;
        u16 pb[4];
#pragma unroll
        for (int j = 0; j < 4; ++j) {
          float p = __expf(s_[i][j][r] - mnew);
          ps += p;
          pb[j] = f2bf(p);
        }
#pragma unroll
        for (int mk = 1; mk < 16; mk <<= 1) ps += __shfl_xor(ps, mk);
        mrow[i][r] = mnew;
        lsum[i][r] = lsum[i][r] * corr + ps;
#pragma unroll
        for (int j = 0; j < 4; ++j) o[i][j][r] *= corr;
        int prow = i * 16 + lg * 4 + r;
#pragma unroll
        for (int j = 0; j < 4; ++j)
          Ps[wid][prow * 64 + ((j * 16 + lr) ^ ((prow & 7) << 3))] = pb[j];
      }
    }
#pragma unroll
    for (int kk = 0; kk < 2; ++kk) {
      short8 pf[2], vf[4];
#pragma unroll
      for (int i = 0; i < 2; ++i)
        pf[i] = *(const short8*)&Ps[wid][(i * 16 + lr) * 64 + ((kk * 32 + lg * 8) ^ swzc)];
#pragma unroll
      for (int j = 0; j < 4; ++j)
        vf[j] = *(const short8*)&Vs[(j * 16 + lr) * 64 + ((kk * 32 + lg * 8) ^ swzc)];
#pragma unroll
      for (int i = 0; i < 2; ++i)
#pragma unroll
        for (int j = 0; j < 4; ++j)
          o[i][j] = __builtin_amdgcn_mfma_f32_16x16x32_bf16(pf[i], vf[j], o[i][j], 0, 0, 0);
    }
  }
#pragma unroll
  for (int i = 0; i < 2; ++i) {
#pragma unroll
    for (int r = 0; r < 4; ++r) {
      float inv = 1.0f / lsum[i][r];
      int srow = q0 + wid * 32 + i * 16 + lg * 4 + r;
      size_t obase = ((size_t)b * SEQ + srow) * DM + hh * DKh;
#pragma unroll
      for (int j = 0; j < 4; ++j)
        ctx[obase + j * 16 + lr] = f2bf(o[i][j][r] * inv);
    }
  }
}

extern "C" void kernel_launch(void* const* d_in, const int* in_sizes, int n_in,
                              void* d_out, int out_size, void* d_ws, size_t ws_size,
                              hipStream_t stream) {
  const float* x   = (const float*)d_in[0];
  const int*   msk = (const int*)d_in[1];
  const float* wq  = (const float*)d_in[2];
  const float* bq  = (const float*)d_in[3];
  const float* wk  = (const float*)d_in[4];
  const float* bk  = (const float*)d_in[5];
  const float* wv  = (const float*)d_in[6];
  const float* bv  = (const float*)d_in[7];
  const float* wo  = (const float*)d_in[8];
  const float* bo  = (const float*)d_in[9];
  const float* w1  = (const float*)d_in[10];
  const float* b1  = (const float*)d_in[11];
  const float* w2  = (const float*)d_in[12];
  const float* b2  = (const float*)d_in[13];
  const float* a1  = (const float*)d_in[14];
  const float* be1 = (const float*)d_in[15];
  const float* a2  = (const float*)d_in[16];
  const float* be2 = (const float*)d_in[17];
  float* out = (float*)d_out;

  u16* wqT = (u16*)d_ws;
  u16* wkT = wqT + (1u << 20);
  u16* wvT = wkT + (1u << 20);
  u16* woT = wvT + (1u << 20);
  u16* w1T = woT + (1u << 20);
  u16* w2T = w1T + (4u << 20);
  u16* xn  = w2T + (4u << 20);
  u16* qb  = xn  + (8u << 20);
  u16* kb  = qb  + (8u << 20);
  u16* vtb = kb  + (8u << 20);
  u16* ctx = vtb + (8u << 20);
  u16* hb  = qb;  // reuse qb..ctx (exactly 8192*4096 elems) for FFN hidden

  dim3 tb(32, 8);
  transpose_bf16<<<dim3(32, 32), tb, 0, stream>>>(wq, wqT, DM, DM);
  transpose_bf16<<<dim3(32, 32), tb, 0, stream>>>(wk, wkT, DM, DM);
  transpose_bf16<<<dim3(32, 32), tb, 0, stream>>>(wv, wvT, DM, DM);
  transpose_bf16<<<dim3(32, 32), tb, 0, stream>>>(wo, woT, DM, DM);
  transpose_bf16<<<dim3(128, 32), tb, 0, stream>>>(w1, w1T, DM, DFF);
  transpose_bf16<<<dim3(32, 128), tb, 0, stream>>>(w2, w2T, DFF, DM);

  ln_bf16<<<NB * SEQ, 256, 0, stream>>>(x, xn, a1, be1);

  gemm_bf16<0><<<dim3(8, 64), 256, 0, stream>>>(xn, wqT, bq, nullptr, qb, NB * SEQ, DM, DM, 0.125f);
  gemm_bf16<0><<<dim3(8, 64), 256, 0, stream>>>(xn, wkT, bk, nullptr, kb, NB * SEQ, DM, DM, 1.0f);
  gemm_bf16<1><<<dim3(8, 64), 256, 0, stream>>>(xn, wvT, bv, nullptr, vtb, NB * SEQ, DM, DM, 1.0f);

  attn_fwd<<<dim3(SEQ / 128, NB * NH), 256, 0, stream>>>(qb, kb, vtb, msk, ctx);

  gemm_bf16<2><<<dim3(8, 64), 256, 0, stream>>>(ctx, woT, bo, x, out, NB * SEQ, DM, DM, 1.0f);

  ln_bf16<<<NB * SEQ, 256, 0, stream>>>(out, xn, a2, be2);

  gemm_bf16<3><<<dim3(32, 64), 256, 0, stream>>>(xn, w1T, b1, nullptr, hb, NB * SEQ, DFF, DM, 1.0f);
  gemm_bf16<2><<<dim3(8, 64), 256, 0, stream>>>(hb, w2T, b2, out, out, NB * SEQ, DM, DFF, 1.0f);
}

// Round 3
// 509.857 us; speedup vs baseline: 1.2941x; 1.1297x over previous
//
#include <hip/hip_runtime.h>
#include <stdint.h>

typedef unsigned short u16;
typedef __attribute__((ext_vector_type(8))) short short8;
typedef __attribute__((ext_vector_type(4))) float f32x4;
typedef __attribute__((ext_vector_type(4))) u16 u16x4;
typedef __attribute__((ext_vector_type(4))) uint32_t u32x4;

#define NB 4
#define SEQ 2048
#define DM 1024
#define NH 16
#define DKh 64
#define DFF 4096
#define LOG2E 1.44269504089f

__device__ __forceinline__ u16 f2bf(float f) {
  union { float f; uint32_t u; } v; v.f = f;
  uint32_t u = v.u;
  return (u16)((u + 0x7FFFu + ((u >> 16) & 1u)) >> 16);
}

__device__ __forceinline__ uint32_t cvtpk(float lo, float hi) {
  uint32_t r;
  asm("v_cvt_pk_bf16_f32 %0, %1, %2" : "=v"(r) : "v"(lo), "v"(hi));
  return r;
}

__device__ __forceinline__ float fexp2(float x) {
  float r;
  asm("v_exp_f32 %0, %1" : "=v"(r) : "v"(x));
  return r;
}

__device__ __forceinline__ void gl16(const u16* g, u16* l) {
  __builtin_amdgcn_global_load_lds((const __attribute__((address_space(1))) void*)g,
                                   (__attribute__((address_space(3))) void*)l, 16, 0, 0);
}

// ---- transpose + fp32->bf16: dst[C][R] = bf16(src[R][C]) ----
__global__ __launch_bounds__(256) void transpose_bf16(const float* __restrict__ src,
                                                      u16* __restrict__ dst, int R, int C) {
  __shared__ float tile[32][33];
  int tx = threadIdx.x, ty = threadIdx.y;
  int c0 = blockIdx.x * 32, r0 = blockIdx.y * 32;
#pragma unroll
  for (int i = 0; i < 32; i += 8)
    tile[ty + i][tx] = src[(size_t)(r0 + ty + i) * C + c0 + tx];
  __syncthreads();
#pragma unroll
  for (int i = 0; i < 32; i += 8)
    dst[(size_t)(c0 + ty + i) * R + r0 + tx] = f2bf(tile[tx][ty + i]);
}

// ---- custom LayerNorm (scalar alpha/beta, unbiased std, eps on std) -> bf16 ----
__global__ __launch_bounds__(256) void ln_bf16(const float* __restrict__ x,
                                               u16* __restrict__ out,
                                               const float* __restrict__ alpha,
                                               const float* __restrict__ beta) {
  int row = blockIdx.x;
  const float4* xr = (const float4*)(x + (size_t)row * DM);
  int t = threadIdx.x;
  float4 v = xr[t];
  float s = v.x + v.y + v.z + v.w;
  float s2 = v.x * v.x + v.y * v.y + v.z * v.z + v.w * v.w;
#pragma unroll
  for (int m = 1; m < 64; m <<= 1) { s += __shfl_xor(s, m); s2 += __shfl_xor(s2, m); }
  __shared__ float red[8];
  int wid = t >> 6, lane = t & 63;
  if (lane == 0) { red[wid] = s; red[wid + 4] = s2; }
  __syncthreads();
  float S = red[0] + red[1] + red[2] + red[3];
  float S2 = red[4] + red[5] + red[6] + red[7];
  float mean = S * (1.0f / DM);
  float var = fmaxf((S2 - S * mean) * (1.0f / (DM - 1)), 0.0f);
  float inv = alpha[0] / (sqrtf(var) + 1e-6f);
  float bet = beta[0];
  u16x4 o;
  o[0] = f2bf((v.x - mean) * inv + bet);
  o[1] = f2bf((v.y - mean) * inv + bet);
  o[2] = f2bf((v.z - mean) * inv + bet);
  o[3] = f2bf((v.w - mean) * inv + bet);
  *(u16x4*)(out + (size_t)row * DM + t * 4) = o;
}

// ---- GEMM: C[M,N] = A[M,K](bf16) @ W^T[N,K](bf16) + bias, epilogue by MODE ----
template <int MODE>
__global__ __launch_bounds__(256) void gemm_bf16(const u16* __restrict__ A,
                                                 const u16* __restrict__ WT,
                                                 const float* __restrict__ bias,
                                                 const float* __restrict__ resid,
                                                 void* __restrict__ outp,
                                                 int M, int N, int K, float scale) {
  __shared__ u16 As[128 * 64];
  __shared__ u16 Bs[128 * 64];
  int tid = threadIdx.x;
  int wid = tid >> 6, lane = tid & 63;
  int lr = lane & 15, lg = lane >> 4;
  // T1: bijective XCD-aware block swizzle (grids here are all %8 == 0)
  int gx = gridDim.x;
  int lid = blockIdx.y * gx + blockIdx.x;
  int cpx = (gx * gridDim.y) >> 3;
  int swz = (lid & 7) * cpx + (lid >> 3);
  int m0 = (swz / gx) * 128, n0 = (swz % gx) * 128;
  int wm = (wid >> 1) * 64, wn = (wid & 1) * 64;
  int sr = tid >> 3;
  int sc = (tid & 7) * 8;
  const u16* ag = A + (size_t)(m0 + sr) * K + sc;
  const u16* bg = WT + (size_t)(n0 + sr) * K + sc;
  u16* asl = As + (size_t)(tid & ~63) * 8;
  u16* bsl = Bs + (size_t)(tid & ~63) * 8;
  f32x4 acc[4][4] = {};
  for (int kt = 0; kt < K; kt += 64) {
#pragma unroll
    for (int it = 0; it < 4; ++it) {
      gl16(ag + (size_t)(it * 32) * K + kt, asl + it * 2048);
      gl16(bg + (size_t)(it * 32) * K + kt, bsl + it * 2048);
    }
    __syncthreads();
#pragma unroll
    for (int kk = 0; kk < 2; ++kk) {
      short8 af[4], bfr[4];
#pragma unroll
      for (int i = 0; i < 4; ++i)
        af[i] = *(const short8*)&As[(wm + i * 16 + lr) * 64 + kk * 32 + lg * 8];
#pragma unroll
      for (int j = 0; j < 4; ++j)
        bfr[j] = *(const short8*)&Bs[(wn + j * 16 + lr) * 64 + kk * 32 + lg * 8];
#pragma unroll
      for (int i = 0; i < 4; ++i)
#pragma unroll
        for (int j = 0; j < 4; ++j)
          acc[i][j] = __builtin_amdgcn_mfma_f32_16x16x32_bf16(af[i], bfr[j], acc[i][j], 0, 0, 0);
    }
    __syncthreads();
  }
#pragma unroll
  for (int i = 0; i < 4; ++i) {
#pragma unroll
    for (int j = 0; j < 4; ++j) {
      int col = n0 + wn + j * 16 + lr;
      float bi = bias[col];
      int rbase = m0 + wm + i * 16 + lg * 4;
      if (MODE == 0) {
        u16* q = (u16*)outp;
        int hh = col >> 6, dd = col & 63;
#pragma unroll
        for (int r = 0; r < 4; ++r) {
          int row = rbase + r;
          int bb = row >> 11, ss = row & 2047;
          q[((size_t)(bb * NH + hh) * SEQ + ss) * DKh + dd] = f2bf((acc[i][j][r] + bi) * scale);
        }
      } else if (MODE == 1) {
        u16* vt = (u16*)outp;
        int hh = col >> 6, dd = col & 63;
        int bb = rbase >> 11, ss = rbase & 2047;
        u16x4 pk;
#pragma unroll
        for (int r = 0; r < 4; ++r) pk[r] = f2bf(acc[i][j][r] + bi);
        *(u16x4*)&vt[((size_t)(bb * NH + hh) * DKh + dd) * SEQ + ss] = pk;
      } else if (MODE == 2) {
        float* o = (float*)outp;
#pragma unroll
        for (int r = 0; r < 4; ++r) {
          int row = rbase + r;
          size_t idx = (size_t)row * N + col;
          o[idx] = resid[idx] + acc[i][j][r] + bi;
        }
      } else {
        u16* o = (u16*)outp;
#pragma unroll
        for (int r = 0; r < 4; ++r) {
          int row = rbase + r;
          o[(size_t)row * N + col] = f2bf(fmaxf(acc[i][j][r] + bi, 0.0f));
        }
      }
    }
  }
}

// ---- flash attention, swapped-operand form ----
// q pre-scaled by (1/8)*log2(e); k [B,H,S,64]; vt [B,H,64,S]; out ctx bf16 [B,S,DM]
// S^T = mfma(K, Q): lane owns q = lr; kv = j*16 + lg*4 + r  (in-register softmax)
// V staged with kv-permutation pos = (j&1)*32 + lg*8 + (j>>1)*4 + r so that
// P packs straight into the PV B-operand via v_cvt_pk_bf16_f32 (no LDS for P).
// O^T = mfma(V, P): lane owns q = lr (same as softmax state) -> rescale is lane-local.
__global__ __launch_bounds__(256) void attn_fwd(const u16* __restrict__ q,
                                                const u16* __restrict__ k,
                                                const u16* __restrict__ vt,
                                                const int* __restrict__ mask,
                                                u16* __restrict__ ctx) {
  __shared__ u16 Ks[64 * 64];
  __shared__ u16 Vs[64 * 64];
  int tid = threadIdx.x;
  int wid = tid >> 6, lane = tid & 63;
  int lr = lane & 15, lg = lane >> 4;
  int bh = blockIdx.y;
  int b = bh >> 4, hh = bh & 15;
  int q0 = blockIdx.x * 128;
  const u16* qbase = q + (size_t)bh * SEQ * DKh;
  const u16* kbase = k + (size_t)bh * SEQ * DKh;
  const u16* vbase = vt + (size_t)bh * DKh * SEQ;
  const int* mbase = mask + b * SEQ;

  short8 qf[2][2];
#pragma unroll
  for (int i = 0; i < 2; ++i)
#pragma unroll
    for (int kk = 0; kk < 2; ++kk)
      qf[i][kk] = *(const short8*)(qbase + (size_t)(q0 + wid * 32 + i * 16 + lr) * DKh + kk * 32 + lg * 8);

  // staging geometry
  int sr = tid >> 3;            // 0..31
  int scg = (tid & 7) * 8;
  int kwix[2];
#pragma unroll
  for (int it = 0; it < 2; ++it) {
    int r = it * 32 + sr;
    kwix[it] = r * 64 + (scg ^ ((r & 7) << 3));
  }
  // V permuted staging: 8 contiguous source kv -> two 4-chunks at pos1, pos1+8
  int jsrc = scg >> 4;
  int pos1 = (jsrc & 1) * 32 + ((scg & 15) >> 2) * 8 + (jsrc >> 1) * 4;
  int vwix[2][2];
#pragma unroll
  for (int it = 0; it < 2; ++it) {
    int r = it * 32 + sr;
    int sw = (r & 7) << 3;
    vwix[it][0] = r * 64 + (pos1 ^ sw);
    vwix[it][1] = r * 64 + ((pos1 + 8) ^ sw);
  }
  int swzc = (lr & 7) << 3;     // read-side column XOR (rows are *16 + lr)

  short8 ka[2], va[2];
#pragma unroll
  for (int it = 0; it < 2; ++it) {
    int r = it * 32 + sr;
    ka[it] = *(const short8*)(kbase + (size_t)r * DKh + scg);
    va[it] = *(const short8*)(vbase + (size_t)r * SEQ + scg);
  }

  f32x4 ot[2][4] = {};
  float mrow[2] = {-3e38f, -3e38f};
  float lsum[2] = {0.0f, 0.0f};

  for (int kv0 = 0; kv0 < SEQ; kv0 += 64) {
    __syncthreads();
#pragma unroll
    for (int it = 0; it < 2; ++it) {
      *(short8*)&Ks[kwix[it]] = ka[it];
      u16x4 vlo, vhi;
#pragma unroll
      for (int e = 0; e < 4; ++e) { vlo[e] = ((u16*)&va[it])[e]; vhi[e] = ((u16*)&va[it])[e + 4]; }
      *(u16x4*)&Vs[vwix[it][0]] = vlo;
      *(u16x4*)&Vs[vwix[it][1]] = vhi;
    }
    if (kv0 + 64 < SEQ) {
      int nv = kv0 + 64;
#pragma unroll
      for (int it = 0; it < 2; ++it) {
        int r = it * 32 + sr;
        ka[it] = *(const short8*)(kbase + (size_t)(nv + r) * DKh + scg);
        va[it] = *(const short8*)(vbase + (size_t)r * SEQ + nv + scg);
      }
    }
    __syncthreads();

    // S^T = K @ Q^T : lane q = lr, kv = j*16 + lg*4 + r
    f32x4 st[2][4] = {};
#pragma unroll
    for (int kk = 0; kk < 2; ++kk) {
      short8 kf[4];
#pragma unroll
      for (int j = 0; j < 4; ++j)
        kf[j] = *(const short8*)&Ks[(j * 16 + lr) * 64 + ((kk * 32 + lg * 8) ^ swzc)];
#pragma unroll
      for (int i = 0; i < 2; ++i)
#pragma unroll
        for (int j = 0; j < 4; ++j)
          st[i][j] = __builtin_amdgcn_mfma_f32_16x16x32_bf16(kf[j], qf[i][kk], st[i][j], 0, 0, 0);
    }

    // mask bias (shared by both i-blocks)
    float fb[4][4];
#pragma unroll
    for (int j = 0; j < 4; ++j) {
      int4 mi = *(const int4*)(mbase + kv0 + j * 16 + lg * 4);
      fb[j][0] = mi.x ? 0.0f : -1e9f;
      fb[j][1] = mi.y ? 0.0f : -1e9f;
      fb[j][2] = mi.z ? 0.0f : -1e9f;
      fb[j][3] = mi.w ? 0.0f : -1e9f;
    }

    u32x4 pa[2][2];
#pragma unroll
    for (int i = 0; i < 2; ++i) {
      float p[4][4];
      float mx = -3e38f;
#pragma unroll
      for (int j = 0; j < 4; ++j)
#pragma unroll
        for (int r = 0; r < 4; ++r) {
          float s = st[i][j][r] + fb[j][r];
          p[j][r] = s;
          mx = fmaxf(mx, s);
        }
      mx = fmaxf(mx, __shfl_xor(mx, 16));
      mx = fmaxf(mx, __shfl_xor(mx, 32));
      float mnew = fmaxf(mrow[i], mx);
      float corr = fexp2(mrow[i] - mnew);
      float ps = 0.0f;
#pragma unroll
      for (int j = 0; j < 4; ++j)
#pragma unroll
        for (int r = 0; r < 4; ++r) {
          float pv = fexp2(p[j][r] - mnew);
          p[j][r] = pv;
          ps += pv;
        }
      ps += __shfl_xor(ps, 16);
      ps += __shfl_xor(ps, 32);
      mrow[i] = mnew;
      lsum[i] = lsum[i] * corr + ps;
#pragma unroll
      for (int jd = 0; jd < 4; ++jd)
#pragma unroll
        for (int r = 0; r < 4; ++r) ot[i][jd][r] *= corr;
#pragma unroll
      for (int ks = 0; ks < 2; ++ks) {
        pa[i][ks][0] = cvtpk(p[ks][0], p[ks][1]);
        pa[i][ks][1] = cvtpk(p[ks][2], p[ks][3]);
        pa[i][ks][2] = cvtpk(p[ks + 2][0], p[ks + 2][1]);
        pa[i][ks][3] = cvtpk(p[ks + 2][2], p[ks + 2][3]);
      }
    }

    // O^T += V @ P : lane q = lr, d = jd*16 + lg*4 + r
#pragma unroll
    for (int ks = 0; ks < 2; ++ks) {
      short8 vf[4];
#pragma unroll
      for (int jd = 0; jd < 4; ++jd)
        vf[jd] = *(const short8*)&Vs[(jd * 16 + lr) * 64 + ((ks * 32 + lg * 8) ^ swzc)];
#pragma unroll
      for (int i = 0; i < 2; ++i)
#pragma unroll
        for (int jd = 0; jd < 4; ++jd)
          ot[i][jd] = __builtin_amdgcn_mfma_f32_16x16x32_bf16(vf[jd], *(short8*)&pa[i][ks], ot[i][jd], 0, 0, 0);
    }
  }

  // epilogue: O^T -> row-major via per-wave LDS bounce, then coalesced-ish store
  float inv0 = 1.0f / lsum[0], inv1 = 1.0f / lsum[1];
  __syncthreads();
  u16* ep = (wid < 2) ? (Ks + wid * 2048) : (Vs + (wid - 2) * 2048);
#pragma unroll
  for (int i = 0; i < 2; ++i) {
    float inv = i ? inv1 : inv0;
#pragma unroll
    for (int jd = 0; jd < 4; ++jd) {
      uint32_t w0 = cvtpk(ot[i][jd][0] * inv, ot[i][jd][1] * inv);
      uint32_t w1 = cvtpk(ot[i][jd][2] * inv, ot[i][jd][3] * inv);
      uint32_t pk2[2] = {w0, w1};
      *(u16x4*)&ep[(i * 16 + lr) * 64 + ((jd * 16 + lg * 4) ^ swzc)] = *(u16x4*)pk2;
    }
  }
  __syncthreads();
  int q_ = lane >> 1;
  size_t orow = ((size_t)b * SEQ + q0 + wid * 32 + q_) * DM + hh * DKh;
#pragma unroll
  for (int it = 0; it < 4; ++it) {
    int dc = (lane & 1) * 32 + it * 8;
    short8 vv = *(const short8*)&ep[q_ * 64 + (dc ^ ((q_ & 7) << 3))];
    *(short8*)(ctx + orow + dc) = vv;
  }
}

extern "C" void kernel_launch(void* const* d_in, const int* in_sizes, int n_in,
                              void* d_out, int out_size, void* d_ws, size_t ws_size,
                              hipStream_t stream) {
  const float* x   = (const float*)d_in[0];
  const int*   msk = (const int*)d_in[1];
  const float* wq  = (const float*)d_in[2];
  const float* bq  = (const float*)d_in[3];
  const float* wk  = (const float*)d_in[4];
  const float* bk  = (const float*)d_in[5];
  const float* wv  = (const float*)d_in[6];
  const float* bv  = (const float*)d_in[7];
  const float* wo  = (const float*)d_in[8];
  const float* bo  = (const float*)d_in[9];
  const float* w1  = (const float*)d_in[10];
  const float* b1  = (const float*)d_in[11];
  const float* w2  = (const float*)d_in[12];
  const float* b2  = (const float*)d_in[13];
  const float* a1  = (const float*)d_in[14];
  const float* be1 = (const float*)d_in[15];
  const float* a2  = (const float*)d_in[16];
  const float* be2 = (const float*)d_in[17];
  float* out = (float*)d_out;

  u16* wqT = (u16*)d_ws;
  u16* wkT = wqT + (1u << 20);
  u16* wvT = wkT + (1u << 20);
  u16* woT = wvT + (1u << 20);
  u16* w1T = woT + (1u << 20);
  u16* w2T = w1T + (4u << 20);
  u16* xn  = w2T + (4u << 20);
  u16* qb  = xn  + (8u << 20);
  u16* kb  = qb  + (8u << 20);
  u16* vtb = kb  + (8u << 20);
  u16* ctx = vtb + (8u << 20);
  u16* hb  = qb;  // reuse qb..ctx for FFN hidden

  dim3 tb(32, 8);
  transpose_bf16<<<dim3(32, 32), tb, 0, stream>>>(wq, wqT, DM, DM);
  transpose_bf16<<<dim3(32, 32), tb, 0, stream>>>(wk, wkT, DM, DM);
  transpose_bf16<<<dim3(32, 32), tb, 0, stream>>>(wv, wvT, DM, DM);
  transpose_bf16<<<dim3(32, 32), tb, 0, stream>>>(wo, woT, DM, DM);
  transpose_bf16<<<dim3(128, 32), tb, 0, stream>>>(w1, w1T, DM, DFF);
  transpose_bf16<<<dim3(32, 128), tb, 0, stream>>>(w2, w2T, DFF, DM);

  ln_bf16<<<NB * SEQ, 256, 0, stream>>>(x, xn, a1, be1);

  gemm_bf16<0><<<dim3(8, 64), 256, 0, stream>>>(xn, wqT, bq, nullptr, qb, NB * SEQ, DM, DM, 0.125f * LOG2E);
  gemm_bf16<0><<<dim3(8, 64), 256, 0, stream>>>(xn, wkT, bk, nullptr, kb, NB * SEQ, DM, DM, 1.0f);
  gemm_bf16<1><<<dim3(8, 64), 256, 0, stream>>>(xn, wvT, bv, nullptr, vtb, NB * SEQ, DM, DM, 1.0f);

  attn_fwd<<<dim3(SEQ / 128, NB * NH), 256, 0, stream>>>(qb, kb, vtb, msk, ctx);

  gemm_bf16<2><<<dim3(8, 64), 256, 0, stream>>>(ctx, woT, bo, x, out, NB * SEQ, DM, DM, 1.0f);

  ln_bf16<<<NB * SEQ, 256, 0, stream>>>(out, xn, a2, be2);

  gemm_bf16<3><<<dim3(32, 64), 256, 0, stream>>>(xn, w1T, b1, nullptr, hb, NB * SEQ, DFF, DM, 1.0f);
  gemm_bf16<2><<<dim3(8, 64), 256, 0, stream>>>(hb, w2T, b2, out, out, NB * SEQ, DM, DFF, 1.0f);
}

// Round 4
// 472.839 us; speedup vs baseline: 1.3954x; 1.0783x over previous
//
#include <hip/hip_runtime.h>
#include <stdint.h>

typedef unsigned short u16;
typedef __attribute__((ext_vector_type(8))) short short8;
typedef __attribute__((ext_vector_type(4))) float f32x4;
typedef __attribute__((ext_vector_type(4))) u16 u16x4;
typedef __attribute__((ext_vector_type(4))) uint32_t u32x4;

#define NB 4
#define SEQ 2048
#define DM 1024
#define NH 16
#define DKh 64
#define DFF 4096
#define LOG2E 1.44269504089f

__device__ __forceinline__ u16 f2bf(float f) {
  union { float f; uint32_t u; } v; v.f = f;
  uint32_t u = v.u;
  return (u16)((u + 0x7FFFu + ((u >> 16) & 1u)) >> 16);
}

__device__ __forceinline__ uint32_t cvtpk(float lo, float hi) {
  uint32_t r;
  asm("v_cvt_pk_bf16_f32 %0, %1, %2" : "=v"(r) : "v"(lo), "v"(hi));
  return r;
}

__device__ __forceinline__ float fexp2(float x) {
  float r;
  asm("v_exp_f32 %0, %1" : "=v"(r) : "v"(x));
  return r;
}

__device__ __forceinline__ void gl16(const u16* g, u16* l) {
  __builtin_amdgcn_global_load_lds((const __attribute__((address_space(1))) void*)g,
                                   (__attribute__((address_space(3))) void*)l, 16, 0, 0);
}

// ---- transpose + fp32->bf16: dst[C][R] = bf16(src[R][C]) ----
__global__ __launch_bounds__(256) void transpose_bf16(const float* __restrict__ src,
                                                      u16* __restrict__ dst, int R, int C) {
  __shared__ float tile[32][33];
  int tx = threadIdx.x, ty = threadIdx.y;
  int c0 = blockIdx.x * 32, r0 = blockIdx.y * 32;
#pragma unroll
  for (int i = 0; i < 32; i += 8)
    tile[ty + i][tx] = src[(size_t)(r0 + ty + i) * C + c0 + tx];
  __syncthreads();
#pragma unroll
  for (int i = 0; i < 32; i += 8)
    dst[(size_t)(c0 + ty + i) * R + r0 + tx] = f2bf(tile[tx][ty + i]);
}

__global__ __launch_bounds__(256) void bias_cat(const float* __restrict__ bq,
                                                const float* __restrict__ bk,
                                                const float* __restrict__ bv,
                                                float* __restrict__ o) {
  int i = blockIdx.x * 256 + threadIdx.x;
  if (i < 3072) o[i] = (i < 1024) ? bq[i] : ((i < 2048) ? bk[i - 1024] : bv[i - 2048]);
}

// ---- custom LayerNorm (scalar alpha/beta, unbiased std, eps on std) -> bf16 ----
__global__ __launch_bounds__(256) void ln_bf16(const float* __restrict__ x,
                                               u16* __restrict__ out,
                                               const float* __restrict__ alpha,
                                               const float* __restrict__ beta) {
  int row = blockIdx.x;
  const float4* xr = (const float4*)(x + (size_t)row * DM);
  int t = threadIdx.x;
  float4 v = xr[t];
  float s = v.x + v.y + v.z + v.w;
  float s2 = v.x * v.x + v.y * v.y + v.z * v.z + v.w * v.w;
#pragma unroll
  for (int m = 1; m < 64; m <<= 1) { s += __shfl_xor(s, m); s2 += __shfl_xor(s2, m); }
  __shared__ float red[8];
  int wid = t >> 6, lane = t & 63;
  if (lane == 0) { red[wid] = s; red[wid + 4] = s2; }
  __syncthreads();
  float S = red[0] + red[1] + red[2] + red[3];
  float S2 = red[4] + red[5] + red[6] + red[7];
  float mean = S * (1.0f / DM);
  float var = fmaxf((S2 - S * mean) * (1.0f / (DM - 1)), 0.0f);
  float inv = alpha[0] / (sqrtf(var) + 1e-6f);
  float bet = beta[0];
  u16x4 o;
  o[0] = f2bf((v.x - mean) * inv + bet);
  o[1] = f2bf((v.y - mean) * inv + bet);
  o[2] = f2bf((v.z - mean) * inv + bet);
  o[3] = f2bf((v.w - mean) * inv + bet);
  *(u16x4*)(out + (size_t)row * DM + t * 4) = o;
}

// ======== 256x256-tile pipelined GEMM, BK=32, 3-deep LDS ring, counted vmcnt ========
// C[M,N] = A[M,K] @ WT[N,K] + bias. 512 thr = 8 waves (2M x 4N), per-wave 128x64.
// LDS: 3 bufs x (A 256x32 + B 256x32) bf16 = 96 KB. Tile t uses buf t%3; tile t+2
// staged during tile t (A halves in phase A, B halves in phase B); vmcnt(4) at each
// tile-end barrier keeps 4 loads in flight across the barrier (never drains).
// Frag-read swizzle: 16B-chunk c stored at c ^ ((row>>1)&3)  (global src pre-swizzled,
// LDS dest linear for global_load_lds).
// MODE 0: fused QKV epilogue (outp=qb; kb,vtb at +1*(8<<20), +2*(8<<20))
// MODE 3: bf16 relu row-major [M,N]
template <int MODE>
__global__ __launch_bounds__(512, 1) void gemm256(const u16* __restrict__ A,
                                                  const u16* __restrict__ WT,
                                                  const float* __restrict__ bias,
                                                  u16* __restrict__ outp,
                                                  int M, int N, int K, float qscale) {
  extern __shared__ u16 lds[];
  int tid = threadIdx.x;
  int lane = tid & 63, wid = tid >> 6;
  int lr = lane & 15, lg = lane >> 4;
  int wr = wid >> 2, wc = wid & 3;
  int nbx = N >> 8;
  int nwg = (M >> 8) * nbx;
  int lid = blockIdx.x;
  int swz = (lid & 7) * (nwg >> 3) + (lid >> 3);   // grids here are %8 == 0
  int m0 = (swz / nbx) << 8, n0 = (swz % nbx) << 8;

  // staging: each wave covers 16 rows of a 128-row half; dest is linear
  int rowih = wid * 16 + (lane >> 2);       // 0..127 within half
  int cchunk = lane & 3;                    // 16B chunk in 64B row
  int csrc = cchunk ^ ((rowih >> 1) & 3);   // pre-swizzled global source chunk
  size_t a_src = (size_t)(m0 + rowih) * K + csrc * 8;
  size_t b_src = (size_t)(n0 + rowih) * K + csrc * 8;
  u16* a_dst = lds + rowih * 32 + cchunk * 8;
  u16* b_dst = a_dst + 8192;

#define STAGE_A(B_, T_) do { \
    const u16* s_ = A + a_src + (size_t)(T_) * 32; \
    gl16(s_, a_dst + (B_) * 16384); \
    gl16(s_ + (size_t)128 * K, a_dst + (B_) * 16384 + 4096); \
  } while (0)
#define STAGE_B(B_, T_) do { \
    const u16* s_ = WT + b_src + (size_t)(T_) * 32; \
    gl16(s_, b_dst + (B_) * 16384); \
    gl16(s_ + (size_t)128 * K, b_dst + (B_) * 16384 + 4096); \
  } while (0)

  // fragment read offsets (swizzle chunk = lg ^ ((lr>>1)&3), i-independent)
  int rchunk = (lg ^ ((lr >> 1) & 3)) * 8;
  int offA[8], offB[4];
#pragma unroll
  for (int i = 0; i < 8; ++i) offA[i] = (wr * 128 + i * 16 + lr) * 32 + rchunk;
#pragma unroll
  for (int j = 0; j < 4; ++j) offB[j] = (wc * 64 + j * 16 + lr) * 32 + rchunk;

  f32x4 acc[8][4] = {};

  int NT = K >> 5;
  // prologue: tiles 0,1 -> bufs 0,1; wait for tile 0 (leave tile 1's 4 in flight)
  STAGE_A(0, 0); STAGE_B(0, 0);
  STAGE_A(1, 1); STAGE_B(1, 1);
  asm volatile("s_waitcnt vmcnt(4)" ::: "memory");
  __builtin_amdgcn_s_barrier();

  int buf = 0;
  for (int t = 0; t < NT; ++t) {
    const u16* la = lds + buf * 16384;
    const u16* lb = la + 8192;
    int b2 = buf - 1; if (b2 < 0) b2 += 3;   // (buf+2)%3
    // ---- phase A: frags (mh=0) + stage A halves of tile t+2
    short8 af0[4], bfr[4];
#pragma unroll
    for (int i = 0; i < 4; ++i) af0[i] = *(const short8*)&la[offA[i]];
#pragma unroll
    for (int j = 0; j < 4; ++j) bfr[j] = *(const short8*)&lb[offB[j]];
    if (t + 2 < NT) STAGE_A(b2, t + 2);
    __builtin_amdgcn_s_setprio(1);
#pragma unroll
    for (int i = 0; i < 4; ++i)
#pragma unroll
      for (int j = 0; j < 4; ++j)
        acc[i][j] = __builtin_amdgcn_mfma_f32_16x16x32_bf16(af0[i], bfr[j], acc[i][j], 0, 0, 0);
    __builtin_amdgcn_s_setprio(0);
    // ---- phase B: frags (mh=1) + stage B halves of tile t+2
    short8 af1[4];
#pragma unroll
    for (int i = 0; i < 4; ++i) af1[i] = *(const short8*)&la[offA[i + 4]];
    if (t + 2 < NT) STAGE_B(b2, t + 2);
    if (t < NT - 2) asm volatile("s_waitcnt vmcnt(4)" ::: "memory");
    else            asm volatile("s_waitcnt vmcnt(0)" ::: "memory");
    __builtin_amdgcn_s_setprio(1);
#pragma unroll
    for (int i = 0; i < 4; ++i)
#pragma unroll
      for (int j = 0; j < 4; ++j)
        acc[i + 4][j] = __builtin_amdgcn_mfma_f32_16x16x32_bf16(af1[i], bfr[j], acc[i + 4][j], 0, 0, 0);
    __builtin_amdgcn_s_setprio(0);
    __builtin_amdgcn_s_barrier();
    __builtin_amdgcn_sched_barrier(0);
    buf = (buf == 2) ? 0 : buf + 1;
  }
#undef STAGE_A
#undef STAGE_B

  // epilogue
#pragma unroll
  for (int i = 0; i < 8; ++i) {
#pragma unroll
    for (int j = 0; j < 4; ++j) {
      int col = n0 + wc * 64 + j * 16 + lr;
      float bi = bias[col];
      int rbase = m0 + wr * 128 + i * 16 + lg * 4;
      if (MODE == 0) {
        int which = col >> 10, nc = col & 1023;
        int hh = nc >> 6, dd = nc & 63;
        int bb = rbase >> 11, ss = rbase & 2047;
        if (which == 2) {
          u16* vtb = outp + (size_t)2 * (8u << 20);
          u16x4 pk;
#pragma unroll
          for (int r = 0; r < 4; ++r) pk[r] = f2bf(acc[i][j][r] + bi);
          *(u16x4*)&vtb[((size_t)(bb * NH + hh) * DKh + dd) * SEQ + ss] = pk;
        } else {
          u16* dst = outp + (size_t)which * (8u << 20);
          float sc = (which == 0) ? qscale : 1.0f;
#pragma unroll
          for (int r = 0; r < 4; ++r)
            dst[((size_t)(bb * NH + hh) * SEQ + (ss + r)) * DKh + dd] = f2bf((acc[i][j][r] + bi) * sc);
        }
      } else {
#pragma unroll
        for (int r = 0; r < 4; ++r)
          outp[(size_t)(rbase + r) * N + col] = f2bf(fmaxf(acc[i][j][r] + bi, 0.0f));
      }
    }
  }
}

// ---- old 128^2 GEMM (kept for O-proj and FFN2): MODE 2: fp32 resid + acc + bias ----
template <int MODE>
__global__ __launch_bounds__(256) void gemm_bf16(const u16* __restrict__ A,
                                                 const u16* __restrict__ WT,
                                                 const float* __restrict__ bias,
                                                 const float* __restrict__ resid,
                                                 void* __restrict__ outp,
                                                 int M, int N, int K, float scale) {
  __shared__ u16 As[128 * 64];
  __shared__ u16 Bs[128 * 64];
  int tid = threadIdx.x;
  int wid = tid >> 6, lane = tid & 63;
  int lr = lane & 15, lg = lane >> 4;
  int gx = gridDim.x;
  int lid = blockIdx.y * gx + blockIdx.x;
  int cpx = (gx * gridDim.y) >> 3;
  int swz = (lid & 7) * cpx + (lid >> 3);
  int m0 = (swz / gx) * 128, n0 = (swz % gx) * 128;
  int wm = (wid >> 1) * 64, wn = (wid & 1) * 64;
  int sr = tid >> 3;
  int sc = (tid & 7) * 8;
  const u16* ag = A + (size_t)(m0 + sr) * K + sc;
  const u16* bg = WT + (size_t)(n0 + sr) * K + sc;
  u16* asl = As + (size_t)(tid & ~63) * 8;
  u16* bsl = Bs + (size_t)(tid & ~63) * 8;
  f32x4 acc[4][4] = {};
  for (int kt = 0; kt < K; kt += 64) {
#pragma unroll
    for (int it = 0; it < 4; ++it) {
      gl16(ag + (size_t)(it * 32) * K + kt, asl + it * 2048);
      gl16(bg + (size_t)(it * 32) * K + kt, bsl + it * 2048);
    }
    __syncthreads();
#pragma unroll
    for (int kk = 0; kk < 2; ++kk) {
      short8 af[4], bfr[4];
#pragma unroll
      for (int i = 0; i < 4; ++i)
        af[i] = *(const short8*)&As[(wm + i * 16 + lr) * 64 + kk * 32 + lg * 8];
#pragma unroll
      for (int j = 0; j < 4; ++j)
        bfr[j] = *(const short8*)&Bs[(wn + j * 16 + lr) * 64 + kk * 32 + lg * 8];
#pragma unroll
      for (int i = 0; i < 4; ++i)
#pragma unroll
        for (int j = 0; j < 4; ++j)
          acc[i][j] = __builtin_amdgcn_mfma_f32_16x16x32_bf16(af[i], bfr[j], acc[i][j], 0, 0, 0);
    }
    __syncthreads();
  }
#pragma unroll
  for (int i = 0; i < 4; ++i) {
#pragma unroll
    for (int j = 0; j < 4; ++j) {
      int col = n0 + wn + j * 16 + lr;
      float bi = bias[col];
      int rbase = m0 + wm + i * 16 + lg * 4;
      float* o = (float*)outp;
#pragma unroll
      for (int r = 0; r < 4; ++r) {
        int row = rbase + r;
        size_t idx = (size_t)row * N + col;
        o[idx] = resid[idx] + acc[i][j][r] + bi;
      }
    }
  }
}

// ---- flash attention, swapped-operand form (see round-2 notes) ----
__global__ __launch_bounds__(256) void attn_fwd(const u16* __restrict__ q,
                                                const u16* __restrict__ k,
                                                const u16* __restrict__ vt,
                                                const int* __restrict__ mask,
                                                u16* __restrict__ ctx) {
  __shared__ u16 Ks[64 * 64];
  __shared__ u16 Vs[64 * 64];
  int tid = threadIdx.x;
  int wid = tid >> 6, lane = tid & 63;
  int lr = lane & 15, lg = lane >> 4;
  int bh = blockIdx.y;
  int b = bh >> 4, hh = bh & 15;
  int q0 = blockIdx.x * 128;
  const u16* qbase = q + (size_t)bh * SEQ * DKh;
  const u16* kbase = k + (size_t)bh * SEQ * DKh;
  const u16* vbase = vt + (size_t)bh * DKh * SEQ;
  const int* mbase = mask + b * SEQ;

  short8 qf[2][2];
#pragma unroll
  for (int i = 0; i < 2; ++i)
#pragma unroll
    for (int kk = 0; kk < 2; ++kk)
      qf[i][kk] = *(const short8*)(qbase + (size_t)(q0 + wid * 32 + i * 16 + lr) * DKh + kk * 32 + lg * 8);

  int sr = tid >> 3;
  int scg = (tid & 7) * 8;
  int kwix[2];
#pragma unroll
  for (int it = 0; it < 2; ++it) {
    int r = it * 32 + sr;
    kwix[it] = r * 64 + (scg ^ ((r & 7) << 3));
  }
  int jsrc = scg >> 4;
  int pos1 = (jsrc & 1) * 32 + ((scg & 15) >> 2) * 8 + (jsrc >> 1) * 4;
  int vwix[2][2];
#pragma unroll
  for (int it = 0; it < 2; ++it) {
    int r = it * 32 + sr;
    int sw = (r & 7) << 3;
    vwix[it][0] = r * 64 + (pos1 ^ sw);
    vwix[it][1] = r * 64 + ((pos1 + 8) ^ sw);
  }
  int swzc = (lr & 7) << 3;

  short8 ka[2], va[2];
#pragma unroll
  for (int it = 0; it < 2; ++it) {
    int r = it * 32 + sr;
    ka[it] = *(const short8*)(kbase + (size_t)r * DKh + scg);
    va[it] = *(const short8*)(vbase + (size_t)r * SEQ + scg);
  }

  f32x4 ot[2][4] = {};
  float mrow[2] = {-3e38f, -3e38f};
  float lsum[2] = {0.0f, 0.0f};

  for (int kv0 = 0; kv0 < SEQ; kv0 += 64) {
    __syncthreads();
#pragma unroll
    for (int it = 0; it < 2; ++it) {
      *(short8*)&Ks[kwix[it]] = ka[it];
      u16x4 vlo, vhi;
#pragma unroll
      for (int e = 0; e < 4; ++e) { vlo[e] = ((u16*)&va[it])[e]; vhi[e] = ((u16*)&va[it])[e + 4]; }
      *(u16x4*)&Vs[vwix[it][0]] = vlo;
      *(u16x4*)&Vs[vwix[it][1]] = vhi;
    }
    if (kv0 + 64 < SEQ) {
      int nv = kv0 + 64;
#pragma unroll
      for (int it = 0; it < 2; ++it) {
        int r = it * 32 + sr;
        ka[it] = *(const short8*)(kbase + (size_t)(nv + r) * DKh + scg);
        va[it] = *(const short8*)(vbase + (size_t)r * SEQ + nv + scg);
      }
    }
    __syncthreads();

    f32x4 st[2][4] = {};
    __builtin_amdgcn_s_setprio(1);
#pragma unroll
    for (int kk = 0; kk < 2; ++kk) {
      short8 kf[4];
#pragma unroll
      for (int j = 0; j < 4; ++j)
        kf[j] = *(const short8*)&Ks[(j * 16 + lr) * 64 + ((kk * 32 + lg * 8) ^ swzc)];
#pragma unroll
      for (int i = 0; i < 2; ++i)
#pragma unroll
        for (int j = 0; j < 4; ++j)
          st[i][j] = __builtin_amdgcn_mfma_f32_16x16x32_bf16(kf[j], qf[i][kk], st[i][j], 0, 0, 0);
    }
    __builtin_amdgcn_s_setprio(0);

    float fb[4][4];
#pragma unroll
    for (int j = 0; j < 4; ++j) {
      int4 mi = *(const int4*)(mbase + kv0 + j * 16 + lg * 4);
      fb[j][0] = mi.x ? 0.0f : -1e9f;
      fb[j][1] = mi.y ? 0.0f : -1e9f;
      fb[j][2] = mi.z ? 0.0f : -1e9f;
      fb[j][3] = mi.w ? 0.0f : -1e9f;
    }

    u32x4 pa[2][2];
#pragma unroll
    for (int i = 0; i < 2; ++i) {
      float p[4][4];
      float mx = -3e38f;
#pragma unroll
      for (int j = 0; j < 4; ++j)
#pragma unroll
        for (int r = 0; r < 4; ++r) {
          float s = st[i][j][r] + fb[j][r];
          p[j][r] = s;
          mx = fmaxf(mx, s);
        }
      mx = fmaxf(mx, __shfl_xor(mx, 16));
      mx = fmaxf(mx, __shfl_xor(mx, 32));
      float mnew = fmaxf(mrow[i], mx);
      // T13 defer-max: skip rescale when the whole wave's max growth <= 8 (log2 units)
      if (!__all(mnew - mrow[i] <= 8.0f)) {
        float corr = fexp2(mrow[i] - mnew);
        lsum[i] *= corr;
#pragma unroll
        for (int jd = 0; jd < 4; ++jd)
#pragma unroll
          for (int r = 0; r < 4; ++r) ot[i][jd][r] *= corr;
        mrow[i] = mnew;
      }
      float ps = 0.0f;
#pragma unroll
      for (int j = 0; j < 4; ++j)
#pragma unroll
        for (int r = 0; r < 4; ++r) {
          float pv = fexp2(p[j][r] - mrow[i]);
          p[j][r] = pv;
          ps += pv;
        }
      ps += __shfl_xor(ps, 16);
      ps += __shfl_xor(ps, 32);
      lsum[i] += ps;
#pragma unroll
      for (int ks = 0; ks < 2; ++ks) {
        pa[i][ks][0] = cvtpk(p[ks][0], p[ks][1]);
        pa[i][ks][1] = cvtpk(p[ks][2], p[ks][3]);
        pa[i][ks][2] = cvtpk(p[ks + 2][0], p[ks + 2][1]);
        pa[i][ks][3] = cvtpk(p[ks + 2][2], p[ks + 2][3]);
      }
    }

    __builtin_amdgcn_s_setprio(1);
#pragma unroll
    for (int ks = 0; ks < 2; ++ks) {
      short8 vf[4];
#pragma unroll
      for (int jd = 0; jd < 4; ++jd)
        vf[jd] = *(const short8*)&Vs[(jd * 16 + lr) * 64 + ((ks * 32 + lg * 8) ^ swzc)];
#pragma unroll
      for (int i = 0; i < 2; ++i)
#pragma unroll
        for (int jd = 0; jd < 4; ++jd)
          ot[i][jd] = __builtin_amdgcn_mfma_f32_16x16x32_bf16(vf[jd], *(short8*)&pa[i][ks], ot[i][jd], 0, 0, 0);
    }
    __builtin_amdgcn_s_setprio(0);
  }

  float inv0 = 1.0f / lsum[0], inv1 = 1.0f / lsum[1];
  __syncthreads();
  u16* ep = (wid < 2) ? (Ks + wid * 2048) : (Vs + (wid - 2) * 2048);
#pragma unroll
  for (int i = 0; i < 2; ++i) {
    float inv = i ? inv1 : inv0;
#pragma unroll
    for (int jd = 0; jd < 4; ++jd) {
      uint32_t w0 = cvtpk(ot[i][jd][0] * inv, ot[i][jd][1] * inv);
      uint32_t w1 = cvtpk(ot[i][jd][2] * inv, ot[i][jd][3] * inv);
      uint32_t pk2[2] = {w0, w1};
      *(u16x4*)&ep[(i * 16 + lr) * 64 + ((jd * 16 + lg * 4) ^ swzc)] = *(u16x4*)pk2;
    }
  }
  __syncthreads();
  int q_ = lane >> 1;
  size_t orow = ((size_t)b * SEQ + q0 + wid * 32 + q_) * DM + hh * DKh;
#pragma unroll
  for (int it = 0; it < 4; ++it) {
    int dc = (lane & 1) * 32 + it * 8;
    short8 vv = *(const short8*)&ep[q_ * 64 + (dc ^ ((q_ & 7) << 3))];
    *(short8*)(ctx + orow + dc) = vv;
  }
}

extern "C" void kernel_launch(void* const* d_in, const int* in_sizes, int n_in,
                              void* d_out, int out_size, void* d_ws, size_t ws_size,
                              hipStream_t stream) {
  const float* x   = (const float*)d_in[0];
  const int*   msk = (const int*)d_in[1];
  const float* wq  = (const float*)d_in[2];
  const float* bq  = (const float*)d_in[3];
  const float* wk  = (const float*)d_in[4];
  const float* bk  = (const float*)d_in[5];
  const float* wv  = (const float*)d_in[6];
  const float* bv  = (const float*)d_in[7];
  const float* wo  = (const float*)d_in[8];
  const float* bo  = (const float*)d_in[9];
  const float* w1  = (const float*)d_in[10];
  const float* b1  = (const float*)d_in[11];
  const float* w2  = (const float*)d_in[12];
  const float* b2  = (const float*)d_in[13];
  const float* a1  = (const float*)d_in[14];
  const float* be1 = (const float*)d_in[15];
  const float* a2  = (const float*)d_in[16];
  const float* be2 = (const float*)d_in[17];
  float* out = (float*)d_out;

  u16* wqT = (u16*)d_ws;          // wq,wk,wv transposed, contiguous => fused QKV WT
  u16* wkT = wqT + (1u << 20);
  u16* wvT = wkT + (1u << 20);
  u16* woT = wvT + (1u << 20);
  u16* w1T = woT + (1u << 20);
  u16* w2T = w1T + (4u << 20);
  u16* xn  = w2T + (4u << 20);
  u16* qb  = xn  + (8u << 20);
  u16* kb  = qb  + (8u << 20);
  u16* vtb = kb  + (8u << 20);
  u16* ctx = vtb + (8u << 20);
  u16* hb  = qb;                  // FFN hidden reuses qb..ctx (64 MB)
  float* bcat = (float*)ctx;      // QKV fused bias; ctx not live until attn

  (void)hipFuncSetAttribute((const void*)gemm256<0>, hipFuncAttributeMaxDynamicSharedMemorySize, 96 * 1024);
  (void)hipFuncSetAttribute((const void*)gemm256<3>, hipFuncAttributeMaxDynamicSharedMemorySize, 96 * 1024);

  dim3 tb(32, 8);
  transpose_bf16<<<dim3(32, 32), tb, 0, stream>>>(wq, wqT, DM, DM);
  transpose_bf16<<<dim3(32, 32), tb, 0, stream>>>(wk, wkT, DM, DM);
  transpose_bf16<<<dim3(32, 32), tb, 0, stream>>>(wv, wvT, DM, DM);
  transpose_bf16<<<dim3(32, 32), tb, 0, stream>>>(wo, woT, DM, DM);
  transpose_bf16<<<dim3(128, 32), tb, 0, stream>>>(w1, w1T, DM, DFF);
  transpose_bf16<<<dim3(32, 128), tb, 0, stream>>>(w2, w2T, DFF, DM);
  bias_cat<<<12, 256, 0, stream>>>(bq, bk, bv, bcat);

  ln_bf16<<<NB * SEQ, 256, 0, stream>>>(x, xn, a1, be1);

  // fused QKV: N=3072, grid 12*32=384 blocks
  gemm256<0><<<384, 512, 96 * 1024, stream>>>(xn, wqT, bcat, qb, NB * SEQ, 3 * DM, DM, 0.125f * LOG2E);

  attn_fwd<<<dim3(SEQ / 128, NB * NH), 256, 0, stream>>>(qb, kb, vtb, msk, ctx);

  gemm_bf16<2><<<dim3(8, 64), 256, 0, stream>>>(ctx, woT, bo, x, out, NB * SEQ, DM, DM, 1.0f);

  ln_bf16<<<NB * SEQ, 256, 0, stream>>>(out, xn, a2, be2);

  // FFN1: N=4096, grid 16*32=512 blocks
  gemm256<3><<<512, 512, 96 * 1024, stream>>>(xn, w1T, b1, hb, NB * SEQ, DFF, DM, 1.0f);

  gemm_bf16<2><<<dim3(8, 64), 256, 0, stream>>>(hb, w2T, b2, out, out, NB * SEQ, DM, DFF, 1.0f);
}

// Round 5
// 422.910 us; speedup vs baseline: 1.5602x; 1.1181x over previous
//
#include <hip/hip_runtime.h>
#include <stdint.h>

typedef unsigned short u16;
typedef __attribute__((ext_vector_type(8))) short short8;
typedef __attribute__((ext_vector_type(4))) float f32x4;
typedef __attribute__((ext_vector_type(4))) u16 u16x4;
typedef __attribute__((ext_vector_type(4))) uint32_t u32x4;

#define NB 4
#define SEQ 2048
#define DM 1024
#define NH 16
#define DKh 64
#define DFF 4096
#define LOG2E 1.44269504089f

__device__ __forceinline__ u16 f2bf(float f) {
  union { float f; uint32_t u; } v; v.f = f;
  uint32_t u = v.u;
  return (u16)((u + 0x7FFFu + ((u >> 16) & 1u)) >> 16);
}

__device__ __forceinline__ uint32_t cvtpk(float lo, float hi) {
  uint32_t r;
  asm("v_cvt_pk_bf16_f32 %0, %1, %2" : "=v"(r) : "v"(lo), "v"(hi));
  return r;
}

__device__ __forceinline__ float fexp2(float x) {
  float r;
  asm("v_exp_f32 %0, %1" : "=v"(r) : "v"(x));
  return r;
}

__device__ __forceinline__ void gl16(const u16* g, u16* l) {
  __builtin_amdgcn_global_load_lds((const __attribute__((address_space(1))) void*)g,
                                   (__attribute__((address_space(3))) void*)l, 16, 0, 0);
}

// ---- transpose + fp32->bf16: dst[C][R] = bf16(src[R][C]) ----
__global__ __launch_bounds__(256) void transpose_bf16(const float* __restrict__ src,
                                                      u16* __restrict__ dst, int R, int C) {
  __shared__ float tile[32][33];
  int tx = threadIdx.x, ty = threadIdx.y;
  int c0 = blockIdx.x * 32, r0 = blockIdx.y * 32;
#pragma unroll
  for (int i = 0; i < 32; i += 8)
    tile[ty + i][tx] = src[(size_t)(r0 + ty + i) * C + c0 + tx];
  __syncthreads();
#pragma unroll
  for (int i = 0; i < 32; i += 8)
    dst[(size_t)(c0 + ty + i) * R + r0 + tx] = f2bf(tile[tx][ty + i]);
}

__global__ __launch_bounds__(256) void bias_cat(const float* __restrict__ bq,
                                                const float* __restrict__ bk,
                                                const float* __restrict__ bv,
                                                float* __restrict__ o) {
  int i = blockIdx.x * 256 + threadIdx.x;
  if (i < 3072) o[i] = (i < 1024) ? bq[i] : ((i < 2048) ? bk[i - 1024] : bv[i - 2048]);
}

__global__ __launch_bounds__(256) void mask_bias(const int* __restrict__ m,
                                                 float* __restrict__ o) {
  int i = blockIdx.x * 256 + threadIdx.x;
  o[i] = m[i] ? 0.0f : -1e9f;
}

// ---- custom LayerNorm (scalar alpha/beta, unbiased std, eps on std) -> bf16 ----
__global__ __launch_bounds__(256) void ln_bf16(const float* __restrict__ x,
                                               u16* __restrict__ out,
                                               const float* __restrict__ alpha,
                                               const float* __restrict__ beta) {
  int row = blockIdx.x;
  const float4* xr = (const float4*)(x + (size_t)row * DM);
  int t = threadIdx.x;
  float4 v = xr[t];
  float s = v.x + v.y + v.z + v.w;
  float s2 = v.x * v.x + v.y * v.y + v.z * v.z + v.w * v.w;
#pragma unroll
  for (int m = 1; m < 64; m <<= 1) { s += __shfl_xor(s, m); s2 += __shfl_xor(s2, m); }
  __shared__ float red[8];
  int wid = t >> 6, lane = t & 63;
  if (lane == 0) { red[wid] = s; red[wid + 4] = s2; }
  __syncthreads();
  float S = red[0] + red[1] + red[2] + red[3];
  float S2 = red[4] + red[5] + red[6] + red[7];
  float mean = S * (1.0f / DM);
  float var = fmaxf((S2 - S * mean) * (1.0f / (DM - 1)), 0.0f);
  float inv = alpha[0] / (sqrtf(var) + 1e-6f);
  float bet = beta[0];
  u16x4 o;
  o[0] = f2bf((v.x - mean) * inv + bet);
  o[1] = f2bf((v.y - mean) * inv + bet);
  o[2] = f2bf((v.z - mean) * inv + bet);
  o[3] = f2bf((v.w - mean) * inv + bet);
  *(u16x4*)(out + (size_t)row * DM + t * 4) = o;
}

// ======== 256x256-tile pipelined GEMM, BK=32, 3-deep LDS ring, counted vmcnt ========
// MODE 0: fused QKV epilogue; MODE 3: bf16 relu row-major
template <int MODE>
__global__ __launch_bounds__(512, 1) void gemm256(const u16* __restrict__ A,
                                                  const u16* __restrict__ WT,
                                                  const float* __restrict__ bias,
                                                  u16* __restrict__ outp,
                                                  int M, int N, int K, float qscale) {
  extern __shared__ u16 lds[];
  int tid = threadIdx.x;
  int lane = tid & 63, wid = tid >> 6;
  int lr = lane & 15, lg = lane >> 4;
  int wr = wid >> 2, wc = wid & 3;
  int nbx = N >> 8;
  int nwg = (M >> 8) * nbx;
  int lid = blockIdx.x;
  int swz = (lid & 7) * (nwg >> 3) + (lid >> 3);
  int m0 = (swz / nbx) << 8, n0 = (swz % nbx) << 8;

  int rowih = wid * 16 + (lane >> 2);
  int cchunk = lane & 3;
  int csrc = cchunk ^ ((rowih >> 1) & 3);
  size_t a_src = (size_t)(m0 + rowih) * K + csrc * 8;
  size_t b_src = (size_t)(n0 + rowih) * K + csrc * 8;
  u16* a_dst = lds + rowih * 32 + cchunk * 8;
  u16* b_dst = a_dst + 8192;

#define STAGE_A(B_, T_) do { \
    const u16* s_ = A + a_src + (size_t)(T_) * 32; \
    gl16(s_, a_dst + (B_) * 16384); \
    gl16(s_ + (size_t)128 * K, a_dst + (B_) * 16384 + 4096); \
  } while (0)
#define STAGE_B(B_, T_) do { \
    const u16* s_ = WT + b_src + (size_t)(T_) * 32; \
    gl16(s_, b_dst + (B_) * 16384); \
    gl16(s_ + (size_t)128 * K, b_dst + (B_) * 16384 + 4096); \
  } while (0)

  int rchunk = (lg ^ ((lr >> 1) & 3)) * 8;
  int offA[8], offB[4];
#pragma unroll
  for (int i = 0; i < 8; ++i) offA[i] = (wr * 128 + i * 16 + lr) * 32 + rchunk;
#pragma unroll
  for (int j = 0; j < 4; ++j) offB[j] = (wc * 64 + j * 16 + lr) * 32 + rchunk;

  f32x4 acc[8][4] = {};

  int NT = K >> 5;
  STAGE_A(0, 0); STAGE_B(0, 0);
  STAGE_A(1, 1); STAGE_B(1, 1);
  asm volatile("s_waitcnt vmcnt(4)" ::: "memory");
  __builtin_amdgcn_s_barrier();

  int buf = 0;
  for (int t = 0; t < NT; ++t) {
    const u16* la = lds + buf * 16384;
    const u16* lb = la + 8192;
    int b2 = buf - 1; if (b2 < 0) b2 += 3;
    short8 af0[4], bfr[4];
#pragma unroll
    for (int i = 0; i < 4; ++i) af0[i] = *(const short8*)&la[offA[i]];
#pragma unroll
    for (int j = 0; j < 4; ++j) bfr[j] = *(const short8*)&lb[offB[j]];
    if (t + 2 < NT) STAGE_A(b2, t + 2);
    __builtin_amdgcn_s_setprio(1);
#pragma unroll
    for (int i = 0; i < 4; ++i)
#pragma unroll
      for (int j = 0; j < 4; ++j)
        acc[i][j] = __builtin_amdgcn_mfma_f32_16x16x32_bf16(af0[i], bfr[j], acc[i][j], 0, 0, 0);
    __builtin_amdgcn_s_setprio(0);
    short8 af1[4];
#pragma unroll
    for (int i = 0; i < 4; ++i) af1[i] = *(const short8*)&la[offA[i + 4]];
    if (t + 2 < NT) STAGE_B(b2, t + 2);
    if (t < NT - 2) asm volatile("s_waitcnt vmcnt(4)" ::: "memory");
    else            asm volatile("s_waitcnt vmcnt(0)" ::: "memory");
    __builtin_amdgcn_s_setprio(1);
#pragma unroll
    for (int i = 0; i < 4; ++i)
#pragma unroll
      for (int j = 0; j < 4; ++j)
        acc[i + 4][j] = __builtin_amdgcn_mfma_f32_16x16x32_bf16(af1[i], bfr[j], acc[i + 4][j], 0, 0, 0);
    __builtin_amdgcn_s_setprio(0);
    __builtin_amdgcn_s_barrier();
    __builtin_amdgcn_sched_barrier(0);
    buf = (buf == 2) ? 0 : buf + 1;
  }
#undef STAGE_A
#undef STAGE_B

#pragma unroll
  for (int i = 0; i < 8; ++i) {
#pragma unroll
    for (int j = 0; j < 4; ++j) {
      int col = n0 + wc * 64 + j * 16 + lr;
      float bi = bias[col];
      int rbase = m0 + wr * 128 + i * 16 + lg * 4;
      if (MODE == 0) {
        int which = col >> 10, nc = col & 1023;
        int hh = nc >> 6, dd = nc & 63;
        int bb = rbase >> 11, ss = rbase & 2047;
        if (which == 2) {
          u16* vtb = outp + (size_t)2 * (8u << 20);
          u16x4 pk;
#pragma unroll
          for (int r = 0; r < 4; ++r) pk[r] = f2bf(acc[i][j][r] + bi);
          *(u16x4*)&vtb[((size_t)(bb * NH + hh) * DKh + dd) * SEQ + ss] = pk;
        } else {
          u16* dst = outp + (size_t)which * (8u << 20);
          float sc = (which == 0) ? qscale : 1.0f;
#pragma unroll
          for (int r = 0; r < 4; ++r)
            dst[((size_t)(bb * NH + hh) * SEQ + (ss + r)) * DKh + dd] = f2bf((acc[i][j][r] + bi) * sc);
        }
      } else {
#pragma unroll
        for (int r = 0; r < 4; ++r)
          outp[(size_t)(rbase + r) * N + col] = f2bf(fmaxf(acc[i][j][r] + bi, 0.0f));
      }
    }
  }
}

// ======== 256x128-tile pipelined GEMM for N=1024 outputs (O-proj, FFN2) ========
// BK=32, 3-deep LDS ring (72 KB), 512 thr = 8 waves (4M x 2N), per-wave 64x64.
// Epilogue: out fp32 [M][N] = resid + acc + bias (fused residual add).
__global__ __launch_bounds__(512, 4) void gemm_v2(const u16* __restrict__ A,
                                                  const u16* __restrict__ WT,
                                                  const float* __restrict__ bias,
                                                  const float* __restrict__ resid,
                                                  float* __restrict__ outp,
                                                  int M, int N, int K) {
  extern __shared__ u16 lds[];
  int tid = threadIdx.x;
  int lane = tid & 63, wid = tid >> 6;
  int lr = lane & 15, lg = lane >> 4;
  int wr = wid >> 1, wc = wid & 1;
  int nbx = N >> 7;
  int nwg = (M >> 8) * nbx;
  int lid = blockIdx.x;
  int swz = (lid & 7) * (nwg >> 3) + (lid >> 3);
  int m0 = (swz / nbx) << 8, n0 = (swz % nbx) << 7;

  // staging: A 256x32 (2 gl16/thr), B 128x32 (1 gl16/thr); ring buf = 24 KB
  int sr = tid >> 2;                 // 0..127
  int sch = tid & 3;
  int scs = sch ^ ((sr >> 1) & 3);   // pre-swizzled source chunk
  size_t a_src = (size_t)(m0 + sr) * K + scs * 8;
  size_t b_src = (size_t)(n0 + sr) * K + scs * 8;
  u16* a_dst = lds + sr * 32 + sch * 8;
  u16* b_dst = lds + 8192 + sr * 32 + sch * 8;

#define STAGE(B_, T_) do { \
    gl16(A + a_src + (size_t)(T_) * 32, a_dst + (B_) * 12288); \
    gl16(A + a_src + (size_t)128 * K + (size_t)(T_) * 32, a_dst + (B_) * 12288 + 4096); \
    gl16(WT + b_src + (size_t)(T_) * 32, b_dst + (B_) * 12288); \
  } while (0)

  int rchunk = (lg ^ ((lr >> 1) & 3)) * 8;
  int offA[4], offB[4];
#pragma unroll
  for (int i = 0; i < 4; ++i) offA[i] = (wr * 64 + i * 16 + lr) * 32 + rchunk;
#pragma unroll
  for (int j = 0; j < 4; ++j) offB[j] = 8192 + (wc * 64 + j * 16 + lr) * 32 + rchunk;

  f32x4 acc[4][4] = {};

  int NT = K >> 5;
  STAGE(0, 0);
  STAGE(1, 1);
  asm volatile("s_waitcnt vmcnt(3)" ::: "memory");
  __builtin_amdgcn_s_barrier();

  int buf = 0;
  for (int t = 0; t < NT; ++t) {
    const u16* la = lds + buf * 12288;
    int b2 = buf - 1; if (b2 < 0) b2 += 3;
    short8 af[4], bfr[4];
#pragma unroll
    for (int i = 0; i < 4; ++i) af[i] = *(const short8*)&la[offA[i]];
#pragma unroll
    for (int j = 0; j < 4; ++j) bfr[j] = *(const short8*)&la[offB[j]];
    if (t + 2 < NT) STAGE(b2, t + 2);
    __builtin_amdgcn_s_setprio(1);
#pragma unroll
    for (int i = 0; i < 4; ++i)
#pragma unroll
      for (int j = 0; j < 4; ++j)
        acc[i][j] = __builtin_amdgcn_mfma_f32_16x16x32_bf16(af[i], bfr[j], acc[i][j], 0, 0, 0);
    __builtin_amdgcn_s_setprio(0);
    if (t < NT - 2) asm volatile("s_waitcnt vmcnt(3)" ::: "memory");
    else            asm volatile("s_waitcnt vmcnt(0)" ::: "memory");
    __builtin_amdgcn_s_barrier();
    __builtin_amdgcn_sched_barrier(0);
    buf = (buf == 2) ? 0 : buf + 1;
  }
#undef STAGE

#pragma unroll
  for (int i = 0; i < 4; ++i) {
#pragma unroll
    for (int j = 0; j < 4; ++j) {
      int col = n0 + wc * 64 + j * 16 + lr;
      float bi = bias[col];
      int rbase = m0 + wr * 64 + i * 16 + lg * 4;
#pragma unroll
      for (int r = 0; r < 4; ++r) {
        size_t idx = (size_t)(rbase + r) * N + col;
        outp[idx] = resid[idx] + acc[i][j][r] + bi;
      }
    }
  }
}

// ---- flash attention, swapped-operand form (see round-2 notes) ----
__global__ __launch_bounds__(256) void attn_fwd(const u16* __restrict__ q,
                                                const u16* __restrict__ k,
                                                const u16* __restrict__ vt,
                                                const float* __restrict__ fbb,
                                                u16* __restrict__ ctx) {
  __shared__ u16 Ks[64 * 64];
  __shared__ u16 Vs[64 * 64];
  int tid = threadIdx.x;
  int wid = tid >> 6, lane = tid & 63;
  int lr = lane & 15, lg = lane >> 4;
  int bh = blockIdx.y;
  int b = bh >> 4, hh = bh & 15;
  int q0 = blockIdx.x * 128;
  const u16* qbase = q + (size_t)bh * SEQ * DKh;
  const u16* kbase = k + (size_t)bh * SEQ * DKh;
  const u16* vbase = vt + (size_t)bh * DKh * SEQ;
  const float* fbbase = fbb + b * SEQ;

  short8 qf[2][2];
#pragma unroll
  for (int i = 0; i < 2; ++i)
#pragma unroll
    for (int kk = 0; kk < 2; ++kk)
      qf[i][kk] = *(const short8*)(qbase + (size_t)(q0 + wid * 32 + i * 16 + lr) * DKh + kk * 32 + lg * 8);

  int sr = tid >> 3;
  int scg = (tid & 7) * 8;
  int kwix[2];
#pragma unroll
  for (int it = 0; it < 2; ++it) {
    int r = it * 32 + sr;
    kwix[it] = r * 64 + (scg ^ ((r & 7) << 3));
  }
  int jsrc = scg >> 4;
  int pos1 = (jsrc & 1) * 32 + ((scg & 15) >> 2) * 8 + (jsrc >> 1) * 4;
  int vwix[2][2];
#pragma unroll
  for (int it = 0; it < 2; ++it) {
    int r = it * 32 + sr;
    int sw = (r & 7) << 3;
    vwix[it][0] = r * 64 + (pos1 ^ sw);
    vwix[it][1] = r * 64 + ((pos1 + 8) ^ sw);
  }
  int swzc = (lr & 7) << 3;

  short8 ka[2], va[2];
#pragma unroll
  for (int it = 0; it < 2; ++it) {
    int r = it * 32 + sr;
    ka[it] = *(const short8*)(kbase + (size_t)r * DKh + scg);
    va[it] = *(const short8*)(vbase + (size_t)r * SEQ + scg);
  }

  f32x4 ot[2][4] = {};
  float mrow[2] = {-3e38f, -3e38f};
  float lsum[2] = {0.0f, 0.0f};

  for (int kv0 = 0; kv0 < SEQ; kv0 += 64) {
    __syncthreads();
#pragma unroll
    for (int it = 0; it < 2; ++it) {
      *(short8*)&Ks[kwix[it]] = ka[it];
      u16x4 vlo, vhi;
#pragma unroll
      for (int e = 0; e < 4; ++e) { vlo[e] = ((u16*)&va[it])[e]; vhi[e] = ((u16*)&va[it])[e + 4]; }
      *(u16x4*)&Vs[vwix[it][0]] = vlo;
      *(u16x4*)&Vs[vwix[it][1]] = vhi;
    }
    if (kv0 + 64 < SEQ) {
      int nv = kv0 + 64;
#pragma unroll
      for (int it = 0; it < 2; ++it) {
        int r = it * 32 + sr;
        ka[it] = *(const short8*)(kbase + (size_t)(nv + r) * DKh + scg);
        va[it] = *(const short8*)(vbase + (size_t)r * SEQ + nv + scg);
      }
    }
    __syncthreads();

    f32x4 st[2][4] = {};
    __builtin_amdgcn_s_setprio(1);
#pragma unroll
    for (int kk = 0; kk < 2; ++kk) {
      short8 kf[4];
#pragma unroll
      for (int j = 0; j < 4; ++j)
        kf[j] = *(const short8*)&Ks[(j * 16 + lr) * 64 + ((kk * 32 + lg * 8) ^ swzc)];
#pragma unroll
      for (int i = 0; i < 2; ++i)
#pragma unroll
        for (int j = 0; j < 4; ++j)
          st[i][j] = __builtin_amdgcn_mfma_f32_16x16x32_bf16(kf[j], qf[i][kk], st[i][j], 0, 0, 0);
    }
    __builtin_amdgcn_s_setprio(0);

    float fb[4][4];
#pragma unroll
    for (int j = 0; j < 4; ++j) {
      float4 f4 = *(const float4*)(fbbase + kv0 + j * 16 + lg * 4);
      fb[j][0] = f4.x; fb[j][1] = f4.y; fb[j][2] = f4.z; fb[j][3] = f4.w;
    }

    u32x4 pa[2][2];
#pragma unroll
    for (int i = 0; i < 2; ++i) {
      float p[4][4];
      float mx = -3e38f;
#pragma unroll
      for (int j = 0; j < 4; ++j)
#pragma unroll
        for (int r = 0; r < 4; ++r) {
          float s = st[i][j][r] + fb[j][r];
          p[j][r] = s;
          mx = fmaxf(mx, s);
        }
      mx = fmaxf(mx, __shfl_xor(mx, 16));
      mx = fmaxf(mx, __shfl_xor(mx, 32));
      float mnew = fmaxf(mrow[i], mx);
      if (!__all(mnew - mrow[i] <= 8.0f)) {
        float corr = fexp2(mrow[i] - mnew);
        lsum[i] *= corr;
#pragma unroll
        for (int jd = 0; jd < 4; ++jd)
#pragma unroll
          for (int r = 0; r < 4; ++r) ot[i][jd][r] *= corr;
        mrow[i] = mnew;
      }
      float ps = 0.0f;
#pragma unroll
      for (int j = 0; j < 4; ++j)
#pragma unroll
        for (int r = 0; r < 4; ++r) {
          float pv = fexp2(p[j][r] - mrow[i]);
          p[j][r] = pv;
          ps += pv;
        }
      ps += __shfl_xor(ps, 16);
      ps += __shfl_xor(ps, 32);
      lsum[i] += ps;
#pragma unroll
      for (int ks = 0; ks < 2; ++ks) {
        pa[i][ks][0] = cvtpk(p[ks][0], p[ks][1]);
        pa[i][ks][1] = cvtpk(p[ks][2], p[ks][3]);
        pa[i][ks][2] = cvtpk(p[ks + 2][0], p[ks + 2][1]);
        pa[i][ks][3] = cvtpk(p[ks + 2][2], p[ks + 2][3]);
      }
    }

    __builtin_amdgcn_s_setprio(1);
#pragma unroll
    for (int ks = 0; ks < 2; ++ks) {
      short8 vf[4];
#pragma unroll
      for (int jd = 0; jd < 4; ++jd)
        vf[jd] = *(const short8*)&Vs[(jd * 16 + lr) * 64 + ((ks * 32 + lg * 8) ^ swzc)];
#pragma unroll
      for (int i = 0; i < 2; ++i)
#pragma unroll
        for (int jd = 0; jd < 4; ++jd)
          ot[i][jd] = __builtin_amdgcn_mfma_f32_16x16x32_bf16(vf[jd], *(short8*)&pa[i][ks], ot[i][jd], 0, 0, 0);
    }
    __builtin_amdgcn_s_setprio(0);
  }

  float inv0 = 1.0f / lsum[0], inv1 = 1.0f / lsum[1];
  __syncthreads();
  u16* ep = (wid < 2) ? (Ks + wid * 2048) : (Vs + (wid - 2) * 2048);
#pragma unroll
  for (int i = 0; i < 2; ++i) {
    float inv = i ? inv1 : inv0;
#pragma unroll
    for (int jd = 0; jd < 4; ++jd) {
      uint32_t w0 = cvtpk(ot[i][jd][0] * inv, ot[i][jd][1] * inv);
      uint32_t w1 = cvtpk(ot[i][jd][2] * inv, ot[i][jd][3] * inv);
      uint32_t pk2[2] = {w0, w1};
      *(u16x4*)&ep[(i * 16 + lr) * 64 + ((jd * 16 + lg * 4) ^ swzc)] = *(u16x4*)pk2;
    }
  }
  __syncthreads();
  int q_ = lane >> 1;
  size_t orow = ((size_t)b * SEQ + q0 + wid * 32 + q_) * DM + hh * DKh;
#pragma unroll
  for (int it = 0; it < 4; ++it) {
    int dc = (lane & 1) * 32 + it * 8;
    short8 vv = *(const short8*)&ep[q_ * 64 + (dc ^ ((q_ & 7) << 3))];
    *(short8*)(ctx + orow + dc) = vv;
  }
}

extern "C" void kernel_launch(void* const* d_in, const int* in_sizes, int n_in,
                              void* d_out, int out_size, void* d_ws, size_t ws_size,
                              hipStream_t stream) {
  const float* x   = (const float*)d_in[0];
  const int*   msk = (const int*)d_in[1];
  const float* wq  = (const float*)d_in[2];
  const float* bq  = (const float*)d_in[3];
  const float* wk  = (const float*)d_in[4];
  const float* bk  = (const float*)d_in[5];
  const float* wv  = (const float*)d_in[6];
  const float* bv  = (const float*)d_in[7];
  const float* wo  = (const float*)d_in[8];
  const float* bo  = (const float*)d_in[9];
  const float* w1  = (const float*)d_in[10];
  const float* b1  = (const float*)d_in[11];
  const float* w2  = (const float*)d_in[12];
  const float* b2  = (const float*)d_in[13];
  const float* a1  = (const float*)d_in[14];
  const float* be1 = (const float*)d_in[15];
  const float* a2  = (const float*)d_in[16];
  const float* be2 = (const float*)d_in[17];
  float* out = (float*)d_out;

  u16* wqT = (u16*)d_ws;          // wq,wk,wv transposed, contiguous => fused QKV WT
  u16* wkT = wqT + (1u << 20);
  u16* wvT = wkT + (1u << 20);
  u16* woT = wvT + (1u << 20);
  u16* w1T = woT + (1u << 20);
  u16* w2T = w1T + (4u << 20);
  u16* xn  = w2T + (4u << 20);
  u16* qb  = xn  + (8u << 20);
  u16* kb  = qb  + (8u << 20);
  u16* vtb = kb  + (8u << 20);
  u16* ctx = vtb + (8u << 20);
  u16* hb  = qb;                  // FFN hidden reuses qb..ctx (64 MB)
  float* bcat = (float*)ctx;      // QKV fused bias; ctx not live until attn
  float* fbb  = (float*)(ctx + (8u << 20));  // mask bias, 32 KB

  (void)hipFuncSetAttribute((const void*)gemm256<0>, hipFuncAttributeMaxDynamicSharedMemorySize, 96 * 1024);
  (void)hipFuncSetAttribute((const void*)gemm256<3>, hipFuncAttributeMaxDynamicSharedMemorySize, 96 * 1024);
  (void)hipFuncSetAttribute((const void*)gemm_v2, hipFuncAttributeMaxDynamicSharedMemorySize, 72 * 1024);

  dim3 tb(32, 8);
  transpose_bf16<<<dim3(32, 32), tb, 0, stream>>>(wq, wqT, DM, DM);
  transpose_bf16<<<dim3(32, 32), tb, 0, stream>>>(wk, wkT, DM, DM);
  transpose_bf16<<<dim3(32, 32), tb, 0, stream>>>(wv, wvT, DM, DM);
  transpose_bf16<<<dim3(32, 32), tb, 0, stream>>>(wo, woT, DM, DM);
  transpose_bf16<<<dim3(128, 32), tb, 0, stream>>>(w1, w1T, DM, DFF);
  transpose_bf16<<<dim3(32, 128), tb, 0, stream>>>(w2, w2T, DFF, DM);
  bias_cat<<<12, 256, 0, stream>>>(bq, bk, bv, bcat);
  mask_bias<<<32, 256, 0, stream>>>(msk, fbb);

  ln_bf16<<<NB * SEQ, 256, 0, stream>>>(x, xn, a1, be1);

  // fused QKV: N=3072, grid 12*32=384 blocks
  gemm256<0><<<384, 512, 96 * 1024, stream>>>(xn, wqT, bcat, qb, NB * SEQ, 3 * DM, DM, 0.125f * LOG2E);

  attn_fwd<<<dim3(SEQ / 128, NB * NH), 256, 0, stream>>>(qb, kb, vtb, fbb, ctx);

  // O-proj + residual: 256x128 tiles, grid 32*8=256
  gemm_v2<<<256, 512, 72 * 1024, stream>>>(ctx, woT, bo, x, out, NB * SEQ, DM, DM);

  ln_bf16<<<NB * SEQ, 256, 0, stream>>>(out, xn, a2, be2);

  // FFN1: N=4096, grid 16*32=512 blocks
  gemm256<3><<<512, 512, 96 * 1024, stream>>>(xn, w1T, b1, hb, NB * SEQ, DFF, DM, 1.0f);

  // FFN2 + residual: 256x128 tiles, grid 256, K=4096
  gemm_v2<<<256, 512, 72 * 1024, stream>>>(hb, w2T, b2, out, out, NB * SEQ, DM, DFF);
}

// Round 6
// 376.251 us; speedup vs baseline: 1.7537x; 1.1240x over previous
//
#include <hip/hip_runtime.h>
#include <stdint.h>

typedef unsigned short u16;
typedef __attribute__((ext_vector_type(8))) short short8;
typedef __attribute__((ext_vector_type(4))) float f32x4;
typedef __attribute__((ext_vector_type(4))) u16 u16x4;
typedef __attribute__((ext_vector_type(4))) uint32_t u32x4;

#define NB 4
#define SEQ 2048
#define DM 1024
#define NH 16
#define DKh 64
#define DFF 4096
#define LOG2E 1.44269504089f

__device__ __forceinline__ u16 f2bf(float f) {
  union { float f; uint32_t u; } v; v.f = f;
  uint32_t u = v.u;
  return (u16)((u + 0x7FFFu + ((u >> 16) & 1u)) >> 16);
}

__device__ __forceinline__ uint32_t cvtpk(float lo, float hi) {
  uint32_t r;
  asm("v_cvt_pk_bf16_f32 %0, %1, %2" : "=v"(r) : "v"(lo), "v"(hi));
  return r;
}

__device__ __forceinline__ float fexp2(float x) {
  float r;
  asm("v_exp_f32 %0, %1" : "=v"(r) : "v"(x));
  return r;
}

__device__ __forceinline__ void gl16(const u16* g, u16* l) {
  __builtin_amdgcn_global_load_lds((const __attribute__((address_space(1))) void*)g,
                                   (__attribute__((address_space(3))) void*)l, 16, 0, 0);
}

// ---- transpose + fp32->bf16: dst[C][R] = bf16(src[R][C]) ----
__global__ __launch_bounds__(256) void transpose_bf16(const float* __restrict__ src,
                                                      u16* __restrict__ dst, int R, int C) {
  __shared__ float tile[32][33];
  int tx = threadIdx.x, ty = threadIdx.y;
  int c0 = blockIdx.x * 32, r0 = blockIdx.y * 32;
#pragma unroll
  for (int i = 0; i < 32; i += 8)
    tile[ty + i][tx] = src[(size_t)(r0 + ty + i) * C + c0 + tx];
  __syncthreads();
#pragma unroll
  for (int i = 0; i < 32; i += 8)
    dst[(size_t)(c0 + ty + i) * R + r0 + tx] = f2bf(tile[tx][ty + i]);
}

__global__ __launch_bounds__(256) void bias_cat(const float* __restrict__ bq,
                                                const float* __restrict__ bk,
                                                const float* __restrict__ bv,
                                                float* __restrict__ o) {
  int i = blockIdx.x * 256 + threadIdx.x;
  if (i < 3072) o[i] = (i < 1024) ? bq[i] : ((i < 2048) ? bk[i - 1024] : bv[i - 2048]);
}

// ---- per-batch mask compaction: index list, lengths, compacted pad-bias ----
__global__ __launch_bounds__(1024) void compact_idx(const int* __restrict__ msk,
                                                    int* __restrict__ cidx,
                                                    int* __restrict__ lArr,
                                                    int* __restrict__ lpArr,
                                                    float* __restrict__ fbbc) {
  int b = blockIdx.x;
  int t = threadIdx.x;
  int lane = t & 63, w = t >> 6;
  int i0 = t * 2, i1 = t * 2 + 1;
  int m0 = msk[b * SEQ + i0] ? 1 : 0;
  int m1 = msk[b * SEQ + i1] ? 1 : 0;
  int s = m0 + m1;
  int run = s;
#pragma unroll
  for (int d = 1; d < 64; d <<= 1) {
    int v = __shfl_up(run, d);
    if (lane >= d) run += v;
  }
  __shared__ int wtot[16];
  __shared__ int woff[17];
  if (lane == 63) wtot[w] = run;
  __syncthreads();
  if (t == 0) {
    int acc = 0;
#pragma unroll
    for (int i = 0; i < 16; ++i) { woff[i] = acc; acc += wtot[i]; }
    woff[16] = acc;
  }
  __syncthreads();
  int excl = run - s + woff[w];
  if (m0) cidx[b * SEQ + excl] = i0;
  if (m1) cidx[b * SEQ + excl + m0] = i1;
  int L = woff[16];
  int LP = (L + 63) & ~63;
  if (LP == 0) LP = 64;
  if (t == 0) { lArr[b] = L; lpArr[b] = LP; }
  for (int l = t; l < SEQ; l += 1024) {
    if (l >= L) cidx[b * SEQ + l] = 0;
    fbbc[b * SEQ + l] = (l < L) ? 0.0f : -1e9f;
  }
}

// ---- compact V^T columns: vthat[bh][d][l] = vtb[bh][d][cidx[b][l]] ----
__global__ __launch_bounds__(256) void gather_vt(const u16* __restrict__ vtb,
                                                 const int* __restrict__ cidx,
                                                 const int* __restrict__ lpArr,
                                                 u16* __restrict__ vthat) {
  int d = blockIdx.x;
  int bh = blockIdx.y;
  int b = bh >> 4;
  int t = threadIdx.x;
  __shared__ u16 row[SEQ];
  const u16* src = vtb + ((size_t)bh * DKh + d) * SEQ;
  *(short8*)&row[t * 8] = *(const short8*)(src + t * 8);
  __syncthreads();
  int LP = lpArr[b];
  u16* dst = vthat + ((size_t)bh * DKh + d) * SEQ;
  const int* ib = cidx + b * SEQ;
  for (int l2 = t; l2 * 2 < LP; l2 += 256) {
    uint32_t lo = row[ib[l2 * 2]];
    uint32_t hi = row[ib[l2 * 2 + 1]];
    *(uint32_t*)&dst[l2 * 2] = lo | (hi << 16);
  }
}

// ---- custom LayerNorm (scalar alpha/beta, unbiased std, eps on std) -> bf16 ----
__global__ __launch_bounds__(256) void ln_bf16(const float* __restrict__ x,
                                               u16* __restrict__ out,
                                               const float* __restrict__ alpha,
                                               const float* __restrict__ beta) {
  int row = blockIdx.x;
  const float4* xr = (const float4*)(x + (size_t)row * DM);
  int t = threadIdx.x;
  float4 v = xr[t];
  float s = v.x + v.y + v.z + v.w;
  float s2 = v.x * v.x + v.y * v.y + v.z * v.z + v.w * v.w;
#pragma unroll
  for (int m = 1; m < 64; m <<= 1) { s += __shfl_xor(s, m); s2 += __shfl_xor(s2, m); }
  __shared__ float red[8];
  int wid = t >> 6, lane = t & 63;
  if (lane == 0) { red[wid] = s; red[wid + 4] = s2; }
  __syncthreads();
  float S = red[0] + red[1] + red[2] + red[3];
  float S2 = red[4] + red[5] + red[6] + red[7];
  float mean = S * (1.0f / DM);
  float var = fmaxf((S2 - S * mean) * (1.0f / (DM - 1)), 0.0f);
  float inv = alpha[0] / (sqrtf(var) + 1e-6f);
  float bet = beta[0];
  u16x4 o;
  o[0] = f2bf((v.x - mean) * inv + bet);
  o[1] = f2bf((v.y - mean) * inv + bet);
  o[2] = f2bf((v.z - mean) * inv + bet);
  o[3] = f2bf((v.w - mean) * inv + bet);
  *(u16x4*)(out + (size_t)row * DM + t * 4) = o;
}

// ======== 256x256-tile pipelined GEMM, BK=32, 3-deep LDS ring, counted vmcnt ========
// MODE 0: fused QKV epilogue; MODE 3: bf16 relu row-major
template <int MODE>
__global__ __launch_bounds__(512, 1) void gemm256(const u16* __restrict__ A,
                                                  const u16* __restrict__ WT,
                                                  const float* __restrict__ bias,
                                                  u16* __restrict__ outp,
                                                  int M, int N, int K, float qscale) {
  extern __shared__ u16 lds[];
  int tid = threadIdx.x;
  int lane = tid & 63, wid = tid >> 6;
  int lr = lane & 15, lg = lane >> 4;
  int wr = wid >> 2, wc = wid & 3;
  int nbx = N >> 8;
  int nwg = (M >> 8) * nbx;
  int lid = blockIdx.x;
  int swz = (lid & 7) * (nwg >> 3) + (lid >> 3);
  int m0 = (swz / nbx) << 8, n0 = (swz % nbx) << 8;

  int rowih = wid * 16 + (lane >> 2);
  int cchunk = lane & 3;
  int csrc = cchunk ^ ((rowih >> 1) & 3);
  size_t a_src = (size_t)(m0 + rowih) * K + csrc * 8;
  size_t b_src = (size_t)(n0 + rowih) * K + csrc * 8;
  u16* a_dst = lds + rowih * 32 + cchunk * 8;
  u16* b_dst = a_dst + 8192;

#define STAGE_A(B_, T_) do { \
    const u16* s_ = A + a_src + (size_t)(T_) * 32; \
    gl16(s_, a_dst + (B_) * 16384); \
    gl16(s_ + (size_t)128 * K, a_dst + (B_) * 16384 + 4096); \
  } while (0)
#define STAGE_B(B_, T_) do { \
    const u16* s_ = WT + b_src + (size_t)(T_) * 32; \
    gl16(s_, b_dst + (B_) * 16384); \
    gl16(s_ + (size_t)128 * K, b_dst + (B_) * 16384 + 4096); \
  } while (0)

  int rchunk = (lg ^ ((lr >> 1) & 3)) * 8;
  int offA[8], offB[4];
#pragma unroll
  for (int i = 0; i < 8; ++i) offA[i] = (wr * 128 + i * 16 + lr) * 32 + rchunk;
#pragma unroll
  for (int j = 0; j < 4; ++j) offB[j] = (wc * 64 + j * 16 + lr) * 32 + rchunk;

  f32x4 acc[8][4] = {};

  int NT = K >> 5;
  STAGE_A(0, 0); STAGE_B(0, 0);
  STAGE_A(1, 1); STAGE_B(1, 1);
  asm volatile("s_waitcnt vmcnt(4)" ::: "memory");
  __builtin_amdgcn_s_barrier();

  int buf = 0;
  for (int t = 0; t < NT; ++t) {
    const u16* la = lds + buf * 16384;
    const u16* lb = la + 8192;
    int b2 = buf - 1; if (b2 < 0) b2 += 3;
    short8 af0[4], bfr[4];
#pragma unroll
    for (int i = 0; i < 4; ++i) af0[i] = *(const short8*)&la[offA[i]];
#pragma unroll
    for (int j = 0; j < 4; ++j) bfr[j] = *(const short8*)&lb[offB[j]];
    if (t + 2 < NT) STAGE_A(b2, t + 2);
    __builtin_amdgcn_s_setprio(1);
#pragma unroll
    for (int i = 0; i < 4; ++i)
#pragma unroll
      for (int j = 0; j < 4; ++j)
        acc[i][j] = __builtin_amdgcn_mfma_f32_16x16x32_bf16(af0[i], bfr[j], acc[i][j], 0, 0, 0);
    __builtin_amdgcn_s_setprio(0);
    short8 af1[4];
#pragma unroll
    for (int i = 0; i < 4; ++i) af1[i] = *(const short8*)&la[offA[i + 4]];
    if (t + 2 < NT) STAGE_B(b2, t + 2);
    if (t < NT - 2) asm volatile("s_waitcnt vmcnt(4)" ::: "memory");
    else            asm volatile("s_waitcnt vmcnt(0)" ::: "memory");
    __builtin_amdgcn_s_setprio(1);
#pragma unroll
    for (int i = 0; i < 4; ++i)
#pragma unroll
      for (int j = 0; j < 4; ++j)
        acc[i + 4][j] = __builtin_amdgcn_mfma_f32_16x16x32_bf16(af1[i], bfr[j], acc[i + 4][j], 0, 0, 0);
    __builtin_amdgcn_s_setprio(0);
    __builtin_amdgcn_s_barrier();
    __builtin_amdgcn_sched_barrier(0);
    buf = (buf == 2) ? 0 : buf + 1;
  }
#undef STAGE_A
#undef STAGE_B

#pragma unroll
  for (int i = 0; i < 8; ++i) {
#pragma unroll
    for (int j = 0; j < 4; ++j) {
      int col = n0 + wc * 64 + j * 16 + lr;
      float bi = bias[col];
      int rbase = m0 + wr * 128 + i * 16 + lg * 4;
      if (MODE == 0) {
        int which = col >> 10, nc = col & 1023;
        int hh = nc >> 6, dd = nc & 63;
        int bb = rbase >> 11, ss = rbase & 2047;
        if (which == 2) {
          u16* vtb = outp + (size_t)2 * (8u << 20);
          u16x4 pk;
#pragma unroll
          for (int r = 0; r < 4; ++r) pk[r] = f2bf(acc[i][j][r] + bi);
          *(u16x4*)&vtb[((size_t)(bb * NH + hh) * DKh + dd) * SEQ + ss] = pk;
        } else {
          u16* dst = outp + (size_t)which * (8u << 20);
          float sc = (which == 0) ? qscale : 1.0f;
#pragma unroll
          for (int r = 0; r < 4; ++r)
            dst[((size_t)(bb * NH + hh) * SEQ + (ss + r)) * DKh + dd] = f2bf((acc[i][j][r] + bi) * sc);
        }
      } else {
#pragma unroll
        for (int r = 0; r < 4; ++r)
          outp[(size_t)(rbase + r) * N + col] = f2bf(fmaxf(acc[i][j][r] + bi, 0.0f));
      }
    }
  }
}

// ======== 256x128-tile pipelined GEMM for N=1024 outputs (O-proj, FFN2) ========
__global__ __launch_bounds__(512, 4) void gemm_v2(const u16* __restrict__ A,
                                                  const u16* __restrict__ WT,
                                                  const float* __restrict__ bias,
                                                  const float* __restrict__ resid,
                                                  float* __restrict__ outp,
                                                  int M, int N, int K) {
  extern __shared__ u16 lds[];
  int tid = threadIdx.x;
  int lane = tid & 63, wid = tid >> 6;
  int lr = lane & 15, lg = lane >> 4;
  int wr = wid >> 1, wc = wid & 1;
  int nbx = N >> 7;
  int nwg = (M >> 8) * nbx;
  int lid = blockIdx.x;
  int swz = (lid & 7) * (nwg >> 3) + (lid >> 3);
  int m0 = (swz / nbx) << 8, n0 = (swz % nbx) << 7;

  int sr = tid >> 2;
  int sch = tid & 3;
  int scs = sch ^ ((sr >> 1) & 3);
  size_t a_src = (size_t)(m0 + sr) * K + scs * 8;
  size_t b_src = (size_t)(n0 + sr) * K + scs * 8;
  u16* a_dst = lds + sr * 32 + sch * 8;
  u16* b_dst = lds + 8192 + sr * 32 + sch * 8;

#define STAGE(B_, T_) do { \
    gl16(A + a_src + (size_t)(T_) * 32, a_dst + (B_) * 12288); \
    gl16(A + a_src + (size_t)128 * K + (size_t)(T_) * 32, a_dst + (B_) * 12288 + 4096); \
    gl16(WT + b_src + (size_t)(T_) * 32, b_dst + (B_) * 12288); \
  } while (0)

  int rchunk = (lg ^ ((lr >> 1) & 3)) * 8;
  int offA[4], offB[4];
#pragma unroll
  for (int i = 0; i < 4; ++i) offA[i] = (wr * 64 + i * 16 + lr) * 32 + rchunk;
#pragma unroll
  for (int j = 0; j < 4; ++j) offB[j] = 8192 + (wc * 64 + j * 16 + lr) * 32 + rchunk;

  f32x4 acc[4][4] = {};

  int NT = K >> 5;
  STAGE(0, 0);
  STAGE(1, 1);
  asm volatile("s_waitcnt vmcnt(3)" ::: "memory");
  __builtin_amdgcn_s_barrier();

  int buf = 0;
  for (int t = 0; t < NT; ++t) {
    const u16* la = lds + buf * 12288;
    int b2 = buf - 1; if (b2 < 0) b2 += 3;
    short8 af[4], bfr[4];
#pragma unroll
    for (int i = 0; i < 4; ++i) af[i] = *(const short8*)&la[offA[i]];
#pragma unroll
    for (int j = 0; j < 4; ++j) bfr[j] = *(const short8*)&la[offB[j]];
    if (t + 2 < NT) STAGE(b2, t + 2);
    __builtin_amdgcn_s_setprio(1);
#pragma unroll
    for (int i = 0; i < 4; ++i)
#pragma unroll
      for (int j = 0; j < 4; ++j)
        acc[i][j] = __builtin_amdgcn_mfma_f32_16x16x32_bf16(af[i], bfr[j], acc[i][j], 0, 0, 0);
    __builtin_amdgcn_s_setprio(0);
    if (t < NT - 2) asm volatile("s_waitcnt vmcnt(3)" ::: "memory");
    else            asm volatile("s_waitcnt vmcnt(0)" ::: "memory");
    __builtin_amdgcn_s_barrier();
    __builtin_amdgcn_sched_barrier(0);
    buf = (buf == 2) ? 0 : buf + 1;
  }
#undef STAGE

#pragma unroll
  for (int i = 0; i < 4; ++i) {
#pragma unroll
    for (int j = 0; j < 4; ++j) {
      int col = n0 + wc * 64 + j * 16 + lr;
      float bi = bias[col];
      int rbase = m0 + wr * 64 + i * 16 + lg * 4;
#pragma unroll
      for (int r = 0; r < 4; ++r) {
        size_t idx = (size_t)(rbase + r) * N + col;
        outp[idx] = resid[idx] + acc[i][j][r] + bi;
      }
    }
  }
}

// ---- flash attention over COMPACTED kv (swapped-operand form) ----
// k [bh][S][64] uncompacted, rows gathered via cidx at staging time;
// vt = compacted V^T [bh][64][S-strided]; loop runs LP_b/64 tiles; pad bias
// (-1e9) applied only on the tail tile via fbbc (compacted domain).
__global__ __launch_bounds__(256) void attn_fwd(const u16* __restrict__ q,
                                                const u16* __restrict__ k,
                                                const u16* __restrict__ vt,
                                                const int* __restrict__ cidx,
                                                const int* __restrict__ lArr,
                                                const int* __restrict__ lpArr,
                                                const float* __restrict__ fbbc,
                                                u16* __restrict__ ctx) {
  __shared__ u16 Ks[64 * 64];
  __shared__ u16 Vs[64 * 64];
  int tid = threadIdx.x;
  int wid = tid >> 6, lane = tid & 63;
  int lr = lane & 15, lg = lane >> 4;
  int bh = blockIdx.y;
  int b = bh >> 4, hh = bh & 15;
  int q0 = blockIdx.x * 128;
  const u16* qbase = q + (size_t)bh * SEQ * DKh;
  const u16* kbase = k + (size_t)bh * SEQ * DKh;
  const u16* vbase = vt + (size_t)bh * DKh * SEQ;
  const float* fbbase = fbbc + b * SEQ;
  const int* ib = cidx + b * SEQ;
  int Lb = lArr[b];
  int LP = lpArr[b];

  short8 qf[2][2];
#pragma unroll
  for (int i = 0; i < 2; ++i)
#pragma unroll
    for (int kk = 0; kk < 2; ++kk)
      qf[i][kk] = *(const short8*)(qbase + (size_t)(q0 + wid * 32 + i * 16 + lr) * DKh + kk * 32 + lg * 8);

  int sr = tid >> 3;
  int scg = (tid & 7) * 8;
  int kwix[2];
#pragma unroll
  for (int it = 0; it < 2; ++it) {
    int r = it * 32 + sr;
    kwix[it] = r * 64 + (scg ^ ((r & 7) << 3));
  }
  int jsrc = scg >> 4;
  int pos1 = (jsrc & 1) * 32 + ((scg & 15) >> 2) * 8 + (jsrc >> 1) * 4;
  int vwix[2][2];
#pragma unroll
  for (int it = 0; it < 2; ++it) {
    int r = it * 32 + sr;
    int sw = (r & 7) << 3;
    vwix[it][0] = r * 64 + (pos1 ^ sw);
    vwix[it][1] = r * 64 + ((pos1 + 8) ^ sw);
  }
  int swzc = (lr & 7) << 3;

  short8 ka[2], va[2];
  {
    int id0 = ib[sr], id1 = ib[32 + sr];
    ka[0] = *(const short8*)(kbase + (size_t)id0 * DKh + scg);
    ka[1] = *(const short8*)(kbase + (size_t)id1 * DKh + scg);
    va[0] = *(const short8*)(vbase + (size_t)sr * SEQ + scg);
    va[1] = *(const short8*)(vbase + (size_t)(32 + sr) * SEQ + scg);
  }

  f32x4 ot[2][4] = {};
  float mrow[2] = {-3e38f, -3e38f};
  float lsum[2] = {0.0f, 0.0f};

  for (int kv0 = 0; kv0 < LP; kv0 += 64) {
    __syncthreads();
#pragma unroll
    for (int it = 0; it < 2; ++it) {
      *(short8*)&Ks[kwix[it]] = ka[it];
      u16x4 vlo, vhi;
#pragma unroll
      for (int e = 0; e < 4; ++e) { vlo[e] = ((u16*)&va[it])[e]; vhi[e] = ((u16*)&va[it])[e + 4]; }
      *(u16x4*)&Vs[vwix[it][0]] = vlo;
      *(u16x4*)&Vs[vwix[it][1]] = vhi;
    }
    if (kv0 + 64 < LP) {
      int nv = kv0 + 64;
      int id0 = ib[nv + sr], id1 = ib[nv + 32 + sr];
      ka[0] = *(const short8*)(kbase + (size_t)id0 * DKh + scg);
      ka[1] = *(const short8*)(kbase + (size_t)id1 * DKh + scg);
      va[0] = *(const short8*)(vbase + (size_t)sr * SEQ + nv + scg);
      va[1] = *(const short8*)(vbase + (size_t)(32 + sr) * SEQ + nv + scg);
    }
    __syncthreads();

    f32x4 st[2][4] = {};
    __builtin_amdgcn_s_setprio(1);
#pragma unroll
    for (int kk = 0; kk < 2; ++kk) {
      short8 kf[4];
#pragma unroll
      for (int j = 0; j < 4; ++j)
        kf[j] = *(const short8*)&Ks[(j * 16 + lr) * 64 + ((kk * 32 + lg * 8) ^ swzc)];
#pragma unroll
      for (int i = 0; i < 2; ++i)
#pragma unroll
        for (int j = 0; j < 4; ++j)
          st[i][j] = __builtin_amdgcn_mfma_f32_16x16x32_bf16(kf[j], qf[i][kk], st[i][j], 0, 0, 0);
    }
    __builtin_amdgcn_s_setprio(0);

    bool tail = (kv0 + 64 > Lb);

    u32x4 pa[2][2];
#pragma unroll
    for (int i = 0; i < 2; ++i) {
      float p[4][4];
      if (tail) {
#pragma unroll
        for (int j = 0; j < 4; ++j) {
          float4 f4 = *(const float4*)(fbbase + kv0 + j * 16 + lg * 4);
          p[j][0] = st[i][j][0] + f4.x;
          p[j][1] = st[i][j][1] + f4.y;
          p[j][2] = st[i][j][2] + f4.z;
          p[j][3] = st[i][j][3] + f4.w;
        }
      } else {
#pragma unroll
        for (int j = 0; j < 4; ++j)
#pragma unroll
          for (int r = 0; r < 4; ++r) p[j][r] = st[i][j][r];
      }
      float mx = -3e38f;
#pragma unroll
      for (int j = 0; j < 4; ++j)
#pragma unroll
        for (int r = 0; r < 4; ++r) mx = fmaxf(mx, p[j][r]);
      mx = fmaxf(mx, __shfl_xor(mx, 16));
      mx = fmaxf(mx, __shfl_xor(mx, 32));
      float mnew = fmaxf(mrow[i], mx);
      if (!__all(mnew - mrow[i] <= 8.0f)) {
        float corr = fexp2(mrow[i] - mnew);
        lsum[i] *= corr;
#pragma unroll
        for (int jd = 0; jd < 4; ++jd)
#pragma unroll
          for (int r = 0; r < 4; ++r) ot[i][jd][r] *= corr;
        mrow[i] = mnew;
      }
      float ps = 0.0f;
#pragma unroll
      for (int j = 0; j < 4; ++j)
#pragma unroll
        for (int r = 0; r < 4; ++r) {
          float pv = fexp2(p[j][r] - mrow[i]);
          p[j][r] = pv;
          ps += pv;
        }
      ps += __shfl_xor(ps, 16);
      ps += __shfl_xor(ps, 32);
      lsum[i] += ps;
#pragma unroll
      for (int ks = 0; ks < 2; ++ks) {
        pa[i][ks][0] = cvtpk(p[ks][0], p[ks][1]);
        pa[i][ks][1] = cvtpk(p[ks][2], p[ks][3]);
        pa[i][ks][2] = cvtpk(p[ks + 2][0], p[ks + 2][1]);
        pa[i][ks][3] = cvtpk(p[ks + 2][2], p[ks + 2][3]);
      }
    }

    __builtin_amdgcn_s_setprio(1);
#pragma unroll
    for (int ks = 0; ks < 2; ++ks) {
      short8 vf[4];
#pragma unroll
      for (int jd = 0; jd < 4; ++jd)
        vf[jd] = *(const short8*)&Vs[(jd * 16 + lr) * 64 + ((ks * 32 + lg * 8) ^ swzc)];
#pragma unroll
      for (int i = 0; i < 2; ++i)
#pragma unroll
        for (int jd = 0; jd < 4; ++jd)
          ot[i][jd] = __builtin_amdgcn_mfma_f32_16x16x32_bf16(vf[jd], *(short8*)&pa[i][ks], ot[i][jd], 0, 0, 0);
    }
    __builtin_amdgcn_s_setprio(0);
  }

  float inv0 = 1.0f / lsum[0], inv1 = 1.0f / lsum[1];
  __syncthreads();
  u16* ep = (wid < 2) ? (Ks + wid * 2048) : (Vs + (wid - 2) * 2048);
#pragma unroll
  for (int i = 0; i < 2; ++i) {
    float inv = i ? inv1 : inv0;
#pragma unroll
    for (int jd = 0; jd < 4; ++jd) {
      uint32_t w0 = cvtpk(ot[i][jd][0] * inv, ot[i][jd][1] * inv);
      uint32_t w1 = cvtpk(ot[i][jd][2] * inv, ot[i][jd][3] * inv);
      uint32_t pk2[2] = {w0, w1};
      *(u16x4*)&ep[(i * 16 + lr) * 64 + ((jd * 16 + lg * 4) ^ swzc)] = *(u16x4*)pk2;
    }
  }
  __syncthreads();
  int q_ = lane >> 1;
  size_t orow = ((size_t)b * SEQ + q0 + wid * 32 + q_) * DM + hh * DKh;
#pragma unroll
  for (int it = 0; it < 4; ++it) {
    int dc = (lane & 1) * 32 + it * 8;
    short8 vv = *(const short8*)&ep[q_ * 64 + (dc ^ ((q_ & 7) << 3))];
    *(short8*)(ctx + orow + dc) = vv;
  }
}

extern "C" void kernel_launch(void* const* d_in, const int* in_sizes, int n_in,
                              void* d_out, int out_size, void* d_ws, size_t ws_size,
                              hipStream_t stream) {
  const float* x   = (const float*)d_in[0];
  const int*   msk = (const int*)d_in[1];
  const float* wq  = (const float*)d_in[2];
  const float* bq  = (const float*)d_in[3];
  const float* wk  = (const float*)d_in[4];
  const float* bk  = (const float*)d_in[5];
  const float* wv  = (const float*)d_in[6];
  const float* bv  = (const float*)d_in[7];
  const float* wo  = (const float*)d_in[8];
  const float* bo  = (const float*)d_in[9];
  const float* w1  = (const float*)d_in[10];
  const float* b1  = (const float*)d_in[11];
  const float* w2  = (const float*)d_in[12];
  const float* b2  = (const float*)d_in[13];
  const float* a1  = (const float*)d_in[14];
  const float* be1 = (const float*)d_in[15];
  const float* a2  = (const float*)d_in[16];
  const float* be2 = (const float*)d_in[17];
  float* out = (float*)d_out;

  u16* wqT = (u16*)d_ws;
  u16* wkT = wqT + (1u << 20);
  u16* wvT = wkT + (1u << 20);
  u16* woT = wvT + (1u << 20);
  u16* w1T = woT + (1u << 20);
  u16* w2T = w1T + (4u << 20);
  u16* xn  = w2T + (4u << 20);     // also reused as compacted V^T (vthat) during attn
  u16* qb  = xn  + (8u << 20);
  u16* kb  = qb  + (8u << 20);
  u16* vtb = kb  + (8u << 20);
  u16* ctx = vtb + (8u << 20);
  u16* hb  = qb;                   // FFN hidden reuses qb..ctx (64 MB)
  float* bcat = (float*)ctx;       // QKV fused bias; ctx not live until attn
  int*   cidx = (int*)(ctx + (8u << 20));        // 32 KB
  int*   lArr = cidx + NB * SEQ;                 // 16 B
  int*   lpArr = lArr + 16;
  float* fbbc = (float*)(lpArr + 16);            // 32 KB

  (void)hipFuncSetAttribute((const void*)gemm256<0>, hipFuncAttributeMaxDynamicSharedMemorySize, 96 * 1024);
  (void)hipFuncSetAttribute((const void*)gemm256<3>, hipFuncAttributeMaxDynamicSharedMemorySize, 96 * 1024);
  (void)hipFuncSetAttribute((const void*)gemm_v2, hipFuncAttributeMaxDynamicSharedMemorySize, 72 * 1024);

  dim3 tb(32, 8);
  transpose_bf16<<<dim3(32, 32), tb, 0, stream>>>(wq, wqT, DM, DM);
  transpose_bf16<<<dim3(32, 32), tb, 0, stream>>>(wk, wkT, DM, DM);
  transpose_bf16<<<dim3(32, 32), tb, 0, stream>>>(wv, wvT, DM, DM);
  transpose_bf16<<<dim3(32, 32), tb, 0, stream>>>(wo, woT, DM, DM);
  transpose_bf16<<<dim3(128, 32), tb, 0, stream>>>(w1, w1T, DM, DFF);
  transpose_bf16<<<dim3(32, 128), tb, 0, stream>>>(w2, w2T, DFF, DM);
  bias_cat<<<12, 256, 0, stream>>>(bq, bk, bv, bcat);
  compact_idx<<<NB, 1024, 0, stream>>>(msk, cidx, lArr, lpArr, fbbc);

  ln_bf16<<<NB * SEQ, 256, 0, stream>>>(x, xn, a1, be1);

  // fused QKV: N=3072, grid 12*32=384 blocks
  gemm256<0><<<384, 512, 96 * 1024, stream>>>(xn, wqT, bcat, qb, NB * SEQ, 3 * DM, DM, 0.125f * LOG2E);

  // compact V^T into xn (xn is dead between QKV GEMM and LN2)
  gather_vt<<<dim3(DKh, NB * NH), 256, 0, stream>>>(vtb, cidx, lpArr, xn);

  attn_fwd<<<dim3(SEQ / 128, NB * NH), 256, 0, stream>>>(qb, kb, xn, cidx, lArr, lpArr, fbbc, ctx);

  // O-proj + residual: 256x128 tiles, grid 256
  gemm_v2<<<256, 512, 72 * 1024, stream>>>(ctx, woT, bo, x, out, NB * SEQ, DM, DM);

  ln_bf16<<<NB * SEQ, 256, 0, stream>>>(out, xn, a2, be2);

  // FFN1: N=4096, grid 512 blocks
  gemm256<3><<<512, 512, 96 * 1024, stream>>>(xn, w1T, b1, hb, NB * SEQ, DFF, DM, 1.0f);

  // FFN2 + residual: 256x128 tiles, grid 256, K=4096
  gemm_v2<<<256, 512, 72 * 1024, stream>>>(hb, w2T, b2, out, out, NB * SEQ, DM, DFF);
}